// Round 4
// baseline (2514.512 us; speedup 1.0000x reference)
//
#include <hip/hip_runtime.h>

// ---------------------------------------------------------------------------
// MultiHeadAttention, all-fp32 in/out (per reference dtype).
// GEMMs: split-bf16 MFMA (hi+lo, 3 products) for fp32-grade accuracy.
// Attention: fp32 VALU flash (correctness-first; MFMA-ize next round).
// ---------------------------------------------------------------------------

typedef __attribute__((ext_vector_type(8))) short short8;
typedef __attribute__((ext_vector_type(8))) float float8;
typedef __attribute__((ext_vector_type(4))) float f32x4;

#define D_MODEL 1024
#define NHEAD   16
#define HD      64
#define SEQ     2048
#define N3      (3*D_MODEL)     // 3072

static __device__ __forceinline__ float bf2f(short s) {
    unsigned u = ((unsigned)(unsigned short)s) << 16;
    return __builtin_bit_cast(float, u);
}
static __device__ __forceinline__ short f2bf(float f) {
    unsigned u = __builtin_bit_cast(unsigned, f);
    u = (u + 0x7fff + ((u >> 16) & 1)) >> 16;   // RNE
    return (short)u;
}

// ---------------------------------------------------------------------------
// Transpose fp32 [K][N] -> split bf16 hi/lo, each [N][K].  Block (32,8).
// ---------------------------------------------------------------------------
__global__ __launch_bounds__(256) void transpose_split(
    const float* __restrict__ in, short* __restrict__ hi, short* __restrict__ lo,
    int K, int N)
{
    __shared__ float tile[32][33];
    const int n0 = blockIdx.x * 32;
    const int k0 = blockIdx.y * 32;
    const int tx = threadIdx.x, ty = threadIdx.y;
#pragma unroll
    for (int i = 0; i < 4; ++i)
        tile[ty + 8*i][tx] = in[(k0 + ty + 8*i) * N + (n0 + tx)];
    __syncthreads();
#pragma unroll
    for (int i = 0; i < 4; ++i) {
        const float v  = tile[tx][ty + 8*i];
        const short vh = f2bf(v);
        const short vl = f2bf(v - bf2f(vh));
        const int idx  = (n0 + ty + 8*i) * K + (k0 + tx);
        hi[idx] = vh;
        lo[idx] = vl;
    }
}

// ---------------------------------------------------------------------------
// QKV GEMM (split-bf16): C[4096,3072] = x @ Wqkv + bqkv, fp32 in/out.
// A split on the fly; B pre-split transposed. Tile 64x64, BK=32, 4 waves.
// Scatter into Q/K/V fp32, each [bh][s][d].
// ---------------------------------------------------------------------------
__global__ __launch_bounds__(256) void qkv_gemm_split(
    const float* __restrict__ A,
    const short* __restrict__ Bh, const short* __restrict__ Bl,
    const float* __restrict__ bias,
    float* __restrict__ Qo, float* __restrict__ Ko, float* __restrict__ Vo)
{
    __shared__ short Ah[64][40], Al[64][40];   // +8 pad, rows 80B
    __shared__ short Bhs[64][40], Bls[64][40];

    const int tid  = threadIdx.x;
    const int wave = tid >> 6, lane = tid & 63;
    const int q4 = lane >> 4, l16 = lane & 15;
    const int m0 = blockIdx.y * 64;
    const int n0 = blockIdx.x * 64;
    const int sr = tid >> 2;            // 0..63
    const int sc = (tid & 3) * 8;       // 0,8,16,24

    f32x4 acc[4];
#pragma unroll
    for (int c = 0; c < 4; ++c) acc[c] = (f32x4){0.f, 0.f, 0.f, 0.f};

    for (int kt = 0; kt < D_MODEL; kt += 32) {
        const float8 av = *(const float8*)&A[(m0 + sr) * D_MODEL + kt + sc];
        short8 ah, al;
#pragma unroll
        for (int i = 0; i < 8; ++i) {
            ah[i] = f2bf(av[i]);
            al[i] = f2bf(av[i] - bf2f(ah[i]));
        }
        *(short8*)&Ah[sr][sc]  = ah;
        *(short8*)&Al[sr][sc]  = al;
        *(short8*)&Bhs[sr][sc] = *(const short8*)&Bh[(n0 + sr) * D_MODEL + kt + sc];
        *(short8*)&Bls[sr][sc] = *(const short8*)&Bl[(n0 + sr) * D_MODEL + kt + sc];
        __syncthreads();
        const short8 afh = *(const short8*)&Ah[wave * 16 + l16][q4 * 8];
        const short8 afl = *(const short8*)&Al[wave * 16 + l16][q4 * 8];
#pragma unroll
        for (int c = 0; c < 4; ++c) {
            const short8 bfh = *(const short8*)&Bhs[c * 16 + l16][q4 * 8];
            const short8 bfl = *(const short8*)&Bls[c * 16 + l16][q4 * 8];
            acc[c] = __builtin_amdgcn_mfma_f32_16x16x32_bf16(afh, bfh, acc[c], 0, 0, 0);
            acc[c] = __builtin_amdgcn_mfma_f32_16x16x32_bf16(afh, bfl, acc[c], 0, 0, 0);
            acc[c] = __builtin_amdgcn_mfma_f32_16x16x32_bf16(afl, bfh, acc[c], 0, 0, 0);
        }
        __syncthreads();
    }

    // scatter epilogue (ref splits 3072 cols as h*192 + j)
    const int mbase = m0 + wave * 16 + q4 * 4;
#pragma unroll
    for (int c = 0; c < 4; ++c) {
        const int n = n0 + c * 16 + l16;          // 0..3071
        const int h = n / 192;
        const int j = n % 192;
        const float bv = bias[n];
#pragma unroll
        for (int r = 0; r < 4; ++r) {
            const int m = mbase + r;              // 0..4095
            const int b = m >> 11;
            const int s = m & 2047;
            const float o = acc[c][r] + bv;
            const int bh = b * NHEAD + h;
            if (j < 64)        Qo[(bh * SEQ + s) * HD + j] = o;
            else if (j < 128)  Ko[(bh * SEQ + s) * HD + (j - 64)] = o;
            else               Vo[(bh * SEQ + s) * HD + (j - 128)] = o;
        }
    }
}

// ---------------------------------------------------------------------------
// fp32 VALU flash attention: one thread per query, online softmax.
// K/V tiles (32 keys x 64 d) staged in LDS. Grid: 32 bh x 8 qc = 256 blocks.
// ---------------------------------------------------------------------------
__global__ __launch_bounds__(256) void attn_valu(
    const float* __restrict__ Q, const float* __restrict__ K,
    const float* __restrict__ V, float* __restrict__ ctx)
{
    __shared__ float Ksh[32][64];
    __shared__ float Vsh[32][64];

    const int bh = blockIdx.x >> 3;     // 0..31
    const int qc = blockIdx.x & 7;
    const int b  = bh >> 4, h = bh & 15;

    const float* Qp = Q + bh * SEQ * HD;
    const float* Kp = K + bh * SEQ * HD;
    const float* Vp = V + bh * SEQ * HD;

    const int tid = threadIdx.x;
    const int qs  = qc * 256 + tid;

    float qreg[64];
#pragma unroll
    for (int d = 0; d < 64; ++d) qreg[d] = Qp[qs * HD + d];

    float acc[64];
#pragma unroll
    for (int d = 0; d < 64; ++d) acc[d] = 0.f;
    float m = -1.0e30f, l = 0.f;

    const int row = tid >> 3, cc = (tid & 7) * 8;

    for (int kt = 0; kt < SEQ; kt += 32) {
        __syncthreads();
        const float8 kv = *(const float8*)&Kp[(kt + row) * HD + cc];
        const float8 vv = *(const float8*)&Vp[(kt + row) * HD + cc];
#pragma unroll
        for (int i = 0; i < 8; ++i) {
            Ksh[row][cc + i] = kv[i];
            Vsh[row][cc + i] = vv[i];
        }
        __syncthreads();

        for (int kk = 0; kk < 32; ++kk) {
            float s = 0.f;
#pragma unroll
            for (int d = 0; d < 64; ++d) s = fmaf(qreg[d], Ksh[kk][d], s);
            s *= 0.125f;                       // 1/sqrt(64)
            const float mnew  = fmaxf(m, s);
            const float scale = exp2f((m - mnew) * 1.4426950408889634f);
            const float p     = exp2f((s - mnew) * 1.4426950408889634f);
            l = l * scale + p;
#pragma unroll
            for (int d = 0; d < 64; ++d)
                acc[d] = acc[d] * scale + p * Vsh[kk][d];
            m = mnew;
        }
    }

    const float inv = 1.0f / l;
#pragma unroll
    for (int d = 0; d < 64; ++d)
        ctx[(b * SEQ + qs) * D_MODEL + h * HD + d] = acc[d] * inv;
}

// ---------------------------------------------------------------------------
// Output GEMM (split-bf16): out[4096,1024] = ctx @ Wout + bout, fp32 in/out.
// ---------------------------------------------------------------------------
__global__ __launch_bounds__(256) void out_gemm_split(
    const float* __restrict__ A,
    const short* __restrict__ Bh, const short* __restrict__ Bl,
    const float* __restrict__ bias, float* __restrict__ out)
{
    __shared__ short Ah[64][40], Al[64][40];
    __shared__ short Bhs[64][40], Bls[64][40];

    const int tid  = threadIdx.x;
    const int wave = tid >> 6, lane = tid & 63;
    const int q4 = lane >> 4, l16 = lane & 15;
    const int m0 = blockIdx.y * 64;
    const int n0 = blockIdx.x * 64;
    const int sr = tid >> 2;
    const int sc = (tid & 3) * 8;

    f32x4 acc[4];
#pragma unroll
    for (int c = 0; c < 4; ++c) acc[c] = (f32x4){0.f, 0.f, 0.f, 0.f};

    for (int kt = 0; kt < D_MODEL; kt += 32) {
        const float8 av = *(const float8*)&A[(m0 + sr) * D_MODEL + kt + sc];
        short8 ah, al;
#pragma unroll
        for (int i = 0; i < 8; ++i) {
            ah[i] = f2bf(av[i]);
            al[i] = f2bf(av[i] - bf2f(ah[i]));
        }
        *(short8*)&Ah[sr][sc]  = ah;
        *(short8*)&Al[sr][sc]  = al;
        *(short8*)&Bhs[sr][sc] = *(const short8*)&Bh[(n0 + sr) * D_MODEL + kt + sc];
        *(short8*)&Bls[sr][sc] = *(const short8*)&Bl[(n0 + sr) * D_MODEL + kt + sc];
        __syncthreads();
        const short8 afh = *(const short8*)&Ah[wave * 16 + l16][q4 * 8];
        const short8 afl = *(const short8*)&Al[wave * 16 + l16][q4 * 8];
#pragma unroll
        for (int c = 0; c < 4; ++c) {
            const short8 bfh = *(const short8*)&Bhs[c * 16 + l16][q4 * 8];
            const short8 bfl = *(const short8*)&Bls[c * 16 + l16][q4 * 8];
            acc[c] = __builtin_amdgcn_mfma_f32_16x16x32_bf16(afh, bfh, acc[c], 0, 0, 0);
            acc[c] = __builtin_amdgcn_mfma_f32_16x16x32_bf16(afh, bfl, acc[c], 0, 0, 0);
            acc[c] = __builtin_amdgcn_mfma_f32_16x16x32_bf16(afl, bfh, acc[c], 0, 0, 0);
        }
        __syncthreads();
    }

    const int mbase = m0 + wave * 16 + q4 * 4;
#pragma unroll
    for (int c = 0; c < 4; ++c) {
        const int n = n0 + c * 16 + l16;
        const float bv = bias[n];
#pragma unroll
        for (int r = 0; r < 4; ++r)
            out[(mbase + r) * D_MODEL + n] = acc[c][r] + bv;
    }
}

// ---------------------------------------------------------------------------
extern "C" void kernel_launch(void* const* d_in, const int* in_sizes, int n_in,
                              void* d_out, int out_size, void* d_ws, size_t ws_size,
                              hipStream_t stream)
{
    const float* x    = (const float*)d_in[0];   // [2,2048,1024] fp32
    const float* Wqkv = (const float*)d_in[1];   // [1024,3072]   fp32
    const float* bqkv = (const float*)d_in[2];   // [3072]        fp32
    const float* Wout = (const float*)d_in[3];   // [1024,1024]   fp32
    const float* bout = (const float*)d_in[4];   // [1024]        fp32
    float* out = (float*)d_out;                  // [2,2048,1024] fp32

    char* ws = (char*)d_ws;
    short* Wh  = (short*)(ws);                    //  6 MB  Wqkv^T hi [3072][1024]
    short* Wl  = (short*)(ws + 6291456);          //  6 MB  Wqkv^T lo
    short* Woh = (short*)(ws + 12582912);         //  2 MB  Wout^T hi [1024][1024]
    short* Wol = (short*)(ws + 14680064);         //  2 MB  Wout^T lo
    float* Qf  = (float*)(ws + 16777216);         // 16 MB  [32][2048][64]
    float* Kf  = (float*)(ws + 33554432);         // 16 MB
    float* Vf  = (float*)(ws + 50331648);         // 16 MB
    float* ctx = (float*)(ws + 67108864);         // 16 MB  (end = 80 MB)

    transpose_split<<<dim3(96, 32), dim3(32, 8), 0, stream>>>(Wqkv, Wh, Wl, D_MODEL, N3);
    transpose_split<<<dim3(32, 32), dim3(32, 8), 0, stream>>>(Wout, Woh, Wol, D_MODEL, D_MODEL);
    qkv_gemm_split<<<dim3(48, 64), 256, 0, stream>>>(x, Wh, Wl, bqkv, Qf, Kf, Vf);
    attn_valu<<<256, 256, 0, stream>>>(Qf, Kf, Vf, ctx);
    out_gemm_split<<<dim3(16, 64), 256, 0, stream>>>(ctx, Woh, Wol, bout, out);
}

// Round 5
// 436.499 us; speedup vs baseline: 5.7606x; 5.7606x over previous
//
#include <hip/hip_runtime.h>

// ---------------------------------------------------------------------------
// MultiHeadAttention, fp32 in/out.
// QKV + out projections: split-bf16 MFMA (hi+lo, 3 products) ~fp32 accuracy.
// Attention: MFMA flash (bf16 QK^T / PV, fp32 online softmax).
//
// Verified gfx950 MFMA 16x16x32_bf16 layouts (learn_hip m89/m91):
//   A-frag:  lane holds A[m = lane&15][k = (lane>>4)*8 + j], j=0..7
//   B-frag:  lane holds B[k = (lane>>4)*8 + j][n = lane&15]
//   C/D:     lane reg r holds D[row = (lane>>4)*4 + r][col = lane&15]
// ---------------------------------------------------------------------------

typedef __attribute__((ext_vector_type(8))) short short8;
typedef __attribute__((ext_vector_type(8))) float float8;
typedef __attribute__((ext_vector_type(4))) float f32x4;

#define D_MODEL 1024
#define NHEAD   16
#define HD      64
#define SEQ     2048
#define N3      (3*D_MODEL)     // 3072

static __device__ __forceinline__ float bf2f(short s) {
    unsigned u = ((unsigned)(unsigned short)s) << 16;
    return __builtin_bit_cast(float, u);
}
static __device__ __forceinline__ short f2bf(float f) {
    unsigned u = __builtin_bit_cast(unsigned, f);
    u = (u + 0x7fff + ((u >> 16) & 1)) >> 16;   // RNE
    return (short)u;
}

// ---------------------------------------------------------------------------
// Transpose fp32 [K][N] -> split bf16 hi/lo, each [N][K].  Block (32,8).
// ---------------------------------------------------------------------------
__global__ __launch_bounds__(256) void transpose_split(
    const float* __restrict__ in, short* __restrict__ hi, short* __restrict__ lo,
    int K, int N)
{
    __shared__ float tile[32][33];
    const int n0 = blockIdx.x * 32;
    const int k0 = blockIdx.y * 32;
    const int tx = threadIdx.x, ty = threadIdx.y;
#pragma unroll
    for (int i = 0; i < 4; ++i)
        tile[ty + 8*i][tx] = in[(k0 + ty + 8*i) * N + (n0 + tx)];
    __syncthreads();
#pragma unroll
    for (int i = 0; i < 4; ++i) {
        const float v  = tile[tx][ty + 8*i];
        const short vh = f2bf(v);
        const short vl = f2bf(v - bf2f(vh));
        const int idx  = (n0 + ty + 8*i) * K + (k0 + tx);
        hi[idx] = vh;
        lo[idx] = vl;
    }
}

// ---------------------------------------------------------------------------
// QKV GEMM (split-bf16): [4096,3072] = x @ Wqkv + bqkv.
// Epilogue scatters bf16 into Q[bh][s][d], K[bh][s][d], Vt[bh][d][s].
// Tile 64x64, BK=32, 4 waves.
// ---------------------------------------------------------------------------
__global__ __launch_bounds__(256) void qkv_gemm_split(
    const float* __restrict__ A,
    const short* __restrict__ Bh, const short* __restrict__ Bl,
    const float* __restrict__ bias,
    short* __restrict__ Qo, short* __restrict__ Ko, short* __restrict__ Vt)
{
    __shared__ short Ah[64][40], Al[64][40];   // +8 pad, rows 80B
    __shared__ short Bhs[64][40], Bls[64][40];

    const int tid  = threadIdx.x;
    const int wave = tid >> 6, lane = tid & 63;
    const int q4 = lane >> 4, l16 = lane & 15;
    const int m0 = blockIdx.y * 64;
    const int n0 = blockIdx.x * 64;
    const int sr = tid >> 2;            // 0..63
    const int sc = (tid & 3) * 8;       // 0,8,16,24

    f32x4 acc[4];
#pragma unroll
    for (int c = 0; c < 4; ++c) acc[c] = (f32x4){0.f, 0.f, 0.f, 0.f};

    for (int kt = 0; kt < D_MODEL; kt += 32) {
        const float8 av = *(const float8*)&A[(m0 + sr) * D_MODEL + kt + sc];
        short8 ah, al;
#pragma unroll
        for (int i = 0; i < 8; ++i) {
            ah[i] = f2bf(av[i]);
            al[i] = f2bf(av[i] - bf2f(ah[i]));
        }
        *(short8*)&Ah[sr][sc]  = ah;
        *(short8*)&Al[sr][sc]  = al;
        *(short8*)&Bhs[sr][sc] = *(const short8*)&Bh[(n0 + sr) * D_MODEL + kt + sc];
        *(short8*)&Bls[sr][sc] = *(const short8*)&Bl[(n0 + sr) * D_MODEL + kt + sc];
        __syncthreads();
        const short8 afh = *(const short8*)&Ah[wave * 16 + l16][q4 * 8];
        const short8 afl = *(const short8*)&Al[wave * 16 + l16][q4 * 8];
#pragma unroll
        for (int c = 0; c < 4; ++c) {
            const short8 bfh = *(const short8*)&Bhs[c * 16 + l16][q4 * 8];
            const short8 bfl = *(const short8*)&Bls[c * 16 + l16][q4 * 8];
            acc[c] = __builtin_amdgcn_mfma_f32_16x16x32_bf16(afh, bfh, acc[c], 0, 0, 0);
            acc[c] = __builtin_amdgcn_mfma_f32_16x16x32_bf16(afh, bfl, acc[c], 0, 0, 0);
            acc[c] = __builtin_amdgcn_mfma_f32_16x16x32_bf16(afl, bfh, acc[c], 0, 0, 0);
        }
        __syncthreads();
    }

    // scatter epilogue (ref splits 3072 cols as h*192 + j)
    const int mbase = m0 + wave * 16 + q4 * 4;
#pragma unroll
    for (int c = 0; c < 4; ++c) {
        const int n = n0 + c * 16 + l16;          // 0..3071
        const int h = n / 192;
        const int j = n % 192;
        const float bv = bias[n];
#pragma unroll
        for (int r = 0; r < 4; ++r) {
            const int m = mbase + r;              // 0..4095
            const int b = m >> 11;
            const int s = m & 2047;
            const short o = f2bf(acc[c][r] + bv);
            const int bh = b * NHEAD + h;
            if (j < 64)        Qo[(bh * SEQ + s) * HD + j] = o;
            else if (j < 128)  Ko[(bh * SEQ + s) * HD + (j - 64)] = o;
            else               Vt[(bh * HD + (j - 128)) * SEQ + s] = o;
        }
    }
}

// ---------------------------------------------------------------------------
// MFMA flash attention: one block = (bh, 64-query tile). 4 waves x 16 queries.
// Online softmax; K tile 32x64 and Vt tile 64x32 staged in LDS per iter.
// Writes fp32 ctx[(b*SEQ+s)*D_MODEL + h*HD + d].
// ---------------------------------------------------------------------------
__global__ __launch_bounds__(256) void attn_mfma(
    const short* __restrict__ Q, const short* __restrict__ K,
    const short* __restrict__ Vt, float* __restrict__ ctx)
{
    __shared__ short Ks[32][72];        // [key][d]   144B row stride
    __shared__ short Vs[64][40];        // [d][key]   80B row stride
    __shared__ short Ps[4][16][40];     // per-wave P [q][key] 80B stride

    const int bid = blockIdx.x;
    const int bh  = bid >> 5;           // /32 q-blocks per (b,h)
    const int qb  = bid & 31;
    const int b   = bh >> 4, h = bh & 15;

    const short* Qp  = Q  + bh * SEQ * HD;
    const short* Kp  = K  + bh * SEQ * HD;
    const short* Vtp = Vt + bh * HD * SEQ;

    const int tid  = threadIdx.x;
    const int wave = tid >> 6, lane = tid & 63;
    const int q4 = lane >> 4, l16 = lane & 15;

    // this wave's Q fragments (reused across all key tiles)
    const int qrow = qb * 64 + wave * 16 + l16;
    const short8 af0 = *(const short8*)&Qp[qrow * HD + q4 * 8];
    const short8 af1 = *(const short8*)&Qp[qrow * HD + 32 + q4 * 8];

    f32x4 acc[4];
#pragma unroll
    for (int c = 0; c < 4; ++c) acc[c] = (f32x4){0.f, 0.f, 0.f, 0.f};
    float mrow[4], lrow[4];
#pragma unroll
    for (int r = 0; r < 4; ++r) { mrow[r] = -1.0e30f; lrow[r] = 0.f; }

    const float SCALE = 0.125f;               // 1/sqrt(64)
    const float LOG2E = 1.4426950408889634f;

    const int sKr = tid >> 3, sKc = (tid & 7) * 8;   // K staging
    const int sVr = tid >> 2, sVc = (tid & 3) * 8;   // V staging

    for (int kt = 0; kt < SEQ; kt += 32) {
        *(short8*)&Ks[sKr][sKc] = *(const short8*)&Kp[(kt + sKr) * HD + sKc];
        *(short8*)&Vs[sVr][sVc] = *(const short8*)&Vtp[sVr * SEQ + kt + sVc];
        __syncthreads();

        // scores: 2 halves of 16 keys, contraction over d=64 (2 mfma each)
        f32x4 sc[2];
#pragma unroll
        for (int e = 0; e < 2; ++e) {
            sc[e] = (f32x4){0.f, 0.f, 0.f, 0.f};
            short8 b0 = *(const short8*)&Ks[e * 16 + l16][q4 * 8];
            sc[e] = __builtin_amdgcn_mfma_f32_16x16x32_bf16(af0, b0, sc[e], 0, 0, 0);
            short8 b1 = *(const short8*)&Ks[e * 16 + l16][32 + q4 * 8];
            sc[e] = __builtin_amdgcn_mfma_f32_16x16x32_bf16(af1, b1, sc[e], 0, 0, 0);
        }

        // online softmax update (rows = 4*q4 + r; 16 key-cols across quad lanes)
        float p[2][4], alpha[4];
#pragma unroll
        for (int r = 0; r < 4; ++r) {
            float s0 = sc[0][r] * SCALE;
            float s1 = sc[1][r] * SCALE;
            float mx = fmaxf(s0, s1);
#pragma unroll
            for (int msk = 1; msk < 16; msk <<= 1)
                mx = fmaxf(mx, __shfl_xor(mx, msk, 64));
            float mnew = fmaxf(mrow[r], mx);
            alpha[r] = exp2f((mrow[r] - mnew) * LOG2E);
            p[0][r] = exp2f((s0 - mnew) * LOG2E);
            p[1][r] = exp2f((s1 - mnew) * LOG2E);
            float rs = p[0][r] + p[1][r];
#pragma unroll
            for (int msk = 1; msk < 16; msk <<= 1)
                rs += __shfl_xor(rs, msk, 64);
            lrow[r] = lrow[r] * alpha[r] + rs;
            mrow[r] = mnew;
        }
#pragma unroll
        for (int c = 0; c < 4; ++c)
#pragma unroll
            for (int r = 0; r < 4; ++r) acc[c][r] *= alpha[r];

        // P -> LDS (C-layout write), read back as A-frag
#pragma unroll
        for (int e = 0; e < 2; ++e)
#pragma unroll
            for (int r = 0; r < 4; ++r)
                Ps[wave][q4 * 4 + r][e * 16 + l16] = f2bf(p[e][r]);

        const short8 pa = *(const short8*)&Ps[wave][l16][q4 * 8];

        // PV: 4 d-chunks of 16
#pragma unroll
        for (int c = 0; c < 4; ++c) {
            const short8 vf = *(const short8*)&Vs[c * 16 + l16][q4 * 8];
            acc[c] = __builtin_amdgcn_mfma_f32_16x16x32_bf16(pa, vf, acc[c], 0, 0, 0);
        }
        __syncthreads();
    }

    // epilogue
#pragma unroll
    for (int r = 0; r < 4; ++r) {
        const int s = qb * 64 + wave * 16 + q4 * 4 + r;
        const float inv = 1.0f / lrow[r];
#pragma unroll
        for (int c = 0; c < 4; ++c) {
            const int d = c * 16 + l16;
            ctx[(b * SEQ + s) * D_MODEL + h * HD + d] = acc[c][r] * inv;
        }
    }
}

// ---------------------------------------------------------------------------
// Output GEMM (split-bf16): out[4096,1024] = ctx @ Wout + bout, fp32 in/out.
// ---------------------------------------------------------------------------
__global__ __launch_bounds__(256) void out_gemm_split(
    const float* __restrict__ A,
    const short* __restrict__ Bh, const short* __restrict__ Bl,
    const float* __restrict__ bias, float* __restrict__ out)
{
    __shared__ short Ah[64][40], Al[64][40];
    __shared__ short Bhs[64][40], Bls[64][40];

    const int tid  = threadIdx.x;
    const int wave = tid >> 6, lane = tid & 63;
    const int q4 = lane >> 4, l16 = lane & 15;
    const int m0 = blockIdx.y * 64;
    const int n0 = blockIdx.x * 64;
    const int sr = tid >> 2;
    const int sc = (tid & 3) * 8;

    f32x4 acc[4];
#pragma unroll
    for (int c = 0; c < 4; ++c) acc[c] = (f32x4){0.f, 0.f, 0.f, 0.f};

    for (int kt = 0; kt < D_MODEL; kt += 32) {
        const float8 av = *(const float8*)&A[(m0 + sr) * D_MODEL + kt + sc];
        short8 ah, al;
#pragma unroll
        for (int i = 0; i < 8; ++i) {
            ah[i] = f2bf(av[i]);
            al[i] = f2bf(av[i] - bf2f(ah[i]));
        }
        *(short8*)&Ah[sr][sc]  = ah;
        *(short8*)&Al[sr][sc]  = al;
        *(short8*)&Bhs[sr][sc] = *(const short8*)&Bh[(n0 + sr) * D_MODEL + kt + sc];
        *(short8*)&Bls[sr][sc] = *(const short8*)&Bl[(n0 + sr) * D_MODEL + kt + sc];
        __syncthreads();
        const short8 afh = *(const short8*)&Ah[wave * 16 + l16][q4 * 8];
        const short8 afl = *(const short8*)&Al[wave * 16 + l16][q4 * 8];
#pragma unroll
        for (int c = 0; c < 4; ++c) {
            const short8 bfh = *(const short8*)&Bhs[c * 16 + l16][q4 * 8];
            const short8 bfl = *(const short8*)&Bls[c * 16 + l16][q4 * 8];
            acc[c] = __builtin_amdgcn_mfma_f32_16x16x32_bf16(afh, bfh, acc[c], 0, 0, 0);
            acc[c] = __builtin_amdgcn_mfma_f32_16x16x32_bf16(afh, bfl, acc[c], 0, 0, 0);
            acc[c] = __builtin_amdgcn_mfma_f32_16x16x32_bf16(afl, bfh, acc[c], 0, 0, 0);
        }
        __syncthreads();
    }

    const int mbase = m0 + wave * 16 + q4 * 4;
#pragma unroll
    for (int c = 0; c < 4; ++c) {
        const int n = n0 + c * 16 + l16;
        const float bv = bias[n];
#pragma unroll
        for (int r = 0; r < 4; ++r)
            out[(mbase + r) * D_MODEL + n] = acc[c][r] + bv;
    }
}

// ---------------------------------------------------------------------------
extern "C" void kernel_launch(void* const* d_in, const int* in_sizes, int n_in,
                              void* d_out, int out_size, void* d_ws, size_t ws_size,
                              hipStream_t stream)
{
    const float* x    = (const float*)d_in[0];   // [2,2048,1024] fp32
    const float* Wqkv = (const float*)d_in[1];   // [1024,3072]   fp32
    const float* bqkv = (const float*)d_in[2];   // [3072]        fp32
    const float* Wout = (const float*)d_in[3];   // [1024,1024]   fp32
    const float* bout = (const float*)d_in[4];   // [1024]        fp32
    float* out = (float*)d_out;                  // [2,2048,1024] fp32

    char* ws = (char*)d_ws;
    short* Wh  = (short*)(ws);                    //  6 MB  Wqkv^T hi [3072][1024]
    short* Wl  = (short*)(ws + 6291456);          //  6 MB  Wqkv^T lo
    short* Woh = (short*)(ws + 12582912);         //  2 MB  Wout^T hi
    short* Wol = (short*)(ws + 14680064);         //  2 MB  Wout^T lo
    short* Qb  = (short*)(ws + 16777216);         //  8 MB  [32][2048][64] bf16
    short* Kb  = (short*)(ws + 25165824);         //  8 MB
    short* Vtb = (short*)(ws + 33554432);         //  8 MB  [32][64][2048] bf16
    float* ctx = (float*)(ws + 41943040);         // 16 MB  (end ~58 MB)

    transpose_split<<<dim3(96, 32), dim3(32, 8), 0, stream>>>(Wqkv, Wh, Wl, D_MODEL, N3);
    transpose_split<<<dim3(32, 32), dim3(32, 8), 0, stream>>>(Wout, Woh, Wol, D_MODEL, D_MODEL);
    qkv_gemm_split<<<dim3(48, 64), 256, 0, stream>>>(x, Wh, Wl, bqkv, Qb, Kb, Vtb);
    attn_mfma<<<1024, 256, 0, stream>>>(Qb, Kb, Vtb, ctx);
    out_gemm_split<<<dim3(16, 64), 256, 0, stream>>>(ctx, Woh, Wol, bout, out);
}

// Round 6
// 349.603 us; speedup vs baseline: 7.1925x; 1.2486x over previous
//
#include <hip/hip_runtime.h>

// ---------------------------------------------------------------------------
// MultiHeadAttention, fp32 in/out.
// Projections: split-bf16 MFMA (hi+lo, 3 products).
// Attention: transposed-score flash (S^T = K.Q^T, 32x32x16 MFMA) with
//   lane-scalar online softmax, in-register P relayout, seq-split-2 + merge.
//
// Verified gfx950 MFMA layouts:
//  16x16x32: A: lane holds A[m=lane&15][k=(lane>>4)*8+j]; C/D row=(lane>>4)*4+r, col=lane&15
//  32x32x16: A: lane holds A[m=lane&31][k=(lane>>5)*8+j]; B: B[k=(lane>>5)*8+j][n=lane&31]
//            C/D: col=lane&31, row=(reg&3)+8*(reg>>2)+4*(lane>>5)
// ---------------------------------------------------------------------------

typedef __attribute__((ext_vector_type(8)))  short short8;
typedef __attribute__((ext_vector_type(8)))  float float8;
typedef __attribute__((ext_vector_type(4)))  float f32x4;
typedef __attribute__((ext_vector_type(16))) float f32x16;
typedef __attribute__((ext_vector_type(4)))  int   int4v;

#define D_MODEL 1024
#define NHEAD   16
#define HD      64
#define SEQ     2048
#define N3      (3*D_MODEL)
#define MB      (1024*1024)

static __device__ __forceinline__ float bf2f(short s) {
    unsigned u = ((unsigned)(unsigned short)s) << 16;
    return __builtin_bit_cast(float, u);
}
static __device__ __forceinline__ short f2bf(float f) {
    unsigned u = __builtin_bit_cast(unsigned, f);
    u = (u + 0x7fff + ((u >> 16) & 1)) >> 16;   // RNE
    return (short)u;
}
static __device__ __forceinline__ unsigned pkbf(float a, float b) {
    unsigned ua = __builtin_bit_cast(unsigned, a);
    ua = (ua + 0x7fff + ((ua >> 16) & 1)) >> 16;
    unsigned ub = __builtin_bit_cast(unsigned, b);
    ub = (ub + 0x7fff + ((ub >> 16) & 1)) & 0xffff0000u;
    return ua | ub;
}

// ---------------------------------------------------------------------------
// Transpose fp32 [K][N] -> split bf16 hi/lo, each [N][K].
// ---------------------------------------------------------------------------
__global__ __launch_bounds__(256) void transpose_split(
    const float* __restrict__ in, short* __restrict__ hi, short* __restrict__ lo,
    int K, int N)
{
    __shared__ float tile[32][33];
    const int n0 = blockIdx.x * 32;
    const int k0 = blockIdx.y * 32;
    const int tx = threadIdx.x, ty = threadIdx.y;
#pragma unroll
    for (int i = 0; i < 4; ++i)
        tile[ty + 8*i][tx] = in[(k0 + ty + 8*i) * N + (n0 + tx)];
    __syncthreads();
#pragma unroll
    for (int i = 0; i < 4; ++i) {
        const float v  = tile[tx][ty + 8*i];
        const short vh = f2bf(v);
        const short vl = f2bf(v - bf2f(vh));
        const int idx  = (n0 + ty + 8*i) * K + (k0 + tx);
        hi[idx] = vh;
        lo[idx] = vl;
    }
}

// ---------------------------------------------------------------------------
// QKV GEMM (split-bf16). Q is pre-scaled by 0.125*log2(e) (softmax folding).
// Scatter: Q[bh][s][d], K[bh][s][d], Vt[bh][d][s] (bf16).
// ---------------------------------------------------------------------------
__global__ __launch_bounds__(256) void qkv_gemm_split(
    const float* __restrict__ A,
    const short* __restrict__ Bh, const short* __restrict__ Bl,
    const float* __restrict__ bias,
    short* __restrict__ Qo, short* __restrict__ Ko, short* __restrict__ Vt)
{
    __shared__ short Ah[64][40], Al[64][40];
    __shared__ short Bhs[64][40], Bls[64][40];

    const int tid  = threadIdx.x;
    const int wave = tid >> 6, lane = tid & 63;
    const int q4 = lane >> 4, l16 = lane & 15;
    const int m0 = blockIdx.y * 64;
    const int n0 = blockIdx.x * 64;
    const int sr = tid >> 2;
    const int sc = (tid & 3) * 8;

    f32x4 acc[4];
#pragma unroll
    for (int c = 0; c < 4; ++c) acc[c] = (f32x4){0.f, 0.f, 0.f, 0.f};

    for (int kt = 0; kt < D_MODEL; kt += 32) {
        const float8 av = *(const float8*)&A[(m0 + sr) * D_MODEL + kt + sc];
        short8 ah, al;
#pragma unroll
        for (int i = 0; i < 8; ++i) {
            ah[i] = f2bf(av[i]);
            al[i] = f2bf(av[i] - bf2f(ah[i]));
        }
        *(short8*)&Ah[sr][sc]  = ah;
        *(short8*)&Al[sr][sc]  = al;
        *(short8*)&Bhs[sr][sc] = *(const short8*)&Bh[(n0 + sr) * D_MODEL + kt + sc];
        *(short8*)&Bls[sr][sc] = *(const short8*)&Bl[(n0 + sr) * D_MODEL + kt + sc];
        __syncthreads();
        const short8 afh = *(const short8*)&Ah[wave * 16 + l16][q4 * 8];
        const short8 afl = *(const short8*)&Al[wave * 16 + l16][q4 * 8];
#pragma unroll
        for (int c = 0; c < 4; ++c) {
            const short8 bfh = *(const short8*)&Bhs[c * 16 + l16][q4 * 8];
            const short8 bfl = *(const short8*)&Bls[c * 16 + l16][q4 * 8];
            acc[c] = __builtin_amdgcn_mfma_f32_16x16x32_bf16(afh, bfh, acc[c], 0, 0, 0);
            acc[c] = __builtin_amdgcn_mfma_f32_16x16x32_bf16(afh, bfl, acc[c], 0, 0, 0);
            acc[c] = __builtin_amdgcn_mfma_f32_16x16x32_bf16(afl, bfh, acc[c], 0, 0, 0);
        }
        __syncthreads();
    }

    const float SCALE_Q = 0.125f * 1.4426950408889634f;  // 1/sqrt(64) * log2(e)
    const int mbase = m0 + wave * 16 + q4 * 4;
#pragma unroll
    for (int c = 0; c < 4; ++c) {
        const int n = n0 + c * 16 + l16;          // 0..3071
        const int h = n / 192;
        const int j = n % 192;
        const float bv = bias[n];
#pragma unroll
        for (int r = 0; r < 4; ++r) {
            const int m = mbase + r;              // 0..4095
            const int b = m >> 11;
            const int s = m & 2047;
            const float v = acc[c][r] + bv;
            const int bh = b * NHEAD + h;
            if (j < 64)        Qo[(bh * SEQ + s) * HD + j] = f2bf(v * SCALE_Q);
            else if (j < 128)  Ko[(bh * SEQ + s) * HD + (j - 64)] = f2bf(v);
            else               Vt[(bh * HD + (j - 128)) * SEQ + s] = f2bf(v);
        }
    }
}

// ---------------------------------------------------------------------------
// Transposed-score flash attention, seq-split-2.
// Block = (bh, 128-query tile, half). 4 waves x 32 queries each.
// Per 32-key chunk: S^T = K.Q^T (4x mfma 32x32x16), lane-scalar softmax,
// in-register P relayout (shfl_xor 32), out^T += V^T.P^T (4x mfma).
// Writes unnormalized Part[half] fp32 + (m,l) per query.
// ---------------------------------------------------------------------------
__global__ __launch_bounds__(256, 4) void attn_tscore(
    const short* __restrict__ Q, const short* __restrict__ K,
    const short* __restrict__ Vt,
    float* __restrict__ Part0, float* __restrict__ Part1,
    float* __restrict__ ML)
{
    __shared__ __attribute__((aligned(16))) char smem[34816];
    short (*Ks)[72] = (short(*)[72])smem;                 // [32 key][64 d], 144B rows
    short (*Vs)[40] = (short(*)[40])(smem + 4608);        // [64 d][32 key], 80B rows

    const int bh   = blockIdx.x;           // 0..31
    const int qb   = blockIdx.y;           // 0..15 (128 q each)
    const int half = blockIdx.z;           // 0..1
    const int kbase0 = half * 1024;

    const short* Qp  = Q  + bh * SEQ * HD;
    const short* Kp  = K  + bh * SEQ * HD;
    const short* Vtp = Vt + bh * HD * SEQ;
    float* Part = half ? Part1 : Part0;

    const int tid  = threadIdx.x;
    const int wave = tid >> 6, lane = tid & 63;
    const int l5 = lane & 31, h = lane >> 5;
    const int q0w = qb * 128 + wave * 32;

    // Q^T B-frags: lane holds Q[q0w+l5][c*16 + h*8 + j]  (pre-scaled)
    short8 qf[4];
#pragma unroll
    for (int c = 0; c < 4; ++c)
        qf[c] = *(const short8*)&Qp[(q0w + l5) * HD + c * 16 + h * 8];

    f32x16 oacc0 = (f32x16)(0.f), oacc1 = (f32x16)(0.f);
    float m = -1.0e30f, l = 0.f;

    // staging coords
    const int sKr = tid >> 3, sKc = (tid & 7) * 8;    // 32 x 64
    const int sVr = tid >> 2, sVc = (tid & 3) * 8;    // 64 x 32

    for (int kc = 0; kc < 32; ++kc) {
        const int kbase = kbase0 + kc * 32;
        __syncthreads();
        *(short8*)&Ks[sKr][sKc] = *(const short8*)&Kp[(kbase + sKr) * HD + sKc];
        *(short8*)&Vs[sVr][sVc] = *(const short8*)&Vtp[sVr * SEQ + kbase + sVc];
        __syncthreads();

        // S^T[key][q]: A = K rows, B = Q^T
        f32x16 sacc = (f32x16)(0.f);
#pragma unroll
        for (int c = 0; c < 4; ++c) {
            const short8 ka = *(const short8*)&Ks[l5][c * 16 + h * 8];
            sacc = __builtin_amdgcn_mfma_f32_32x32x16_bf16(ka, qf[c], sacc, 0, 0, 0);
        }
        // lane owns query l5; 16 scores (keys (r&3)+8*(r>>2)+4h)

        // max tree + cross-half combine
        float a0 = fmaxf(sacc[0], sacc[8]),  a1 = fmaxf(sacc[1], sacc[9]);
        float a2 = fmaxf(sacc[2], sacc[10]), a3 = fmaxf(sacc[3], sacc[11]);
        float a4 = fmaxf(sacc[4], sacc[12]), a5 = fmaxf(sacc[5], sacc[13]);
        float a6 = fmaxf(sacc[6], sacc[14]), a7 = fmaxf(sacc[7], sacc[15]);
        a0 = fmaxf(a0, a4); a1 = fmaxf(a1, a5); a2 = fmaxf(a2, a6); a3 = fmaxf(a3, a7);
        a0 = fmaxf(fmaxf(a0, a1), fmaxf(a2, a3));
        a0 = fmaxf(a0, __shfl_xor(a0, 32, 64));
        const float mnew  = fmaxf(m, a0);
        const float alpha = exp2f(m - mnew);

        float p[16];
#pragma unroll
        for (int i = 0; i < 16; ++i) p[i] = exp2f(sacc[i] - mnew);

        float s0 = p[0]+p[8], s1 = p[1]+p[9], s2 = p[2]+p[10], s3 = p[3]+p[11];
        float s4 = p[4]+p[12], s5 = p[5]+p[13], s6 = p[6]+p[14], s7 = p[7]+p[15];
        s0 += s4; s1 += s5; s2 += s6; s3 += s7;
        float rs = (s0 + s1) + (s2 + s3);
        rs += __shfl_xor(rs, 32, 64);
        l = l * alpha + rs;
        m = mnew;

#pragma unroll
        for (int i = 0; i < 16; ++i) { oacc0[i] *= alpha; oacc1[i] *= alpha; }

        // pack p -> bf16 pairs; u[t] = keys (base_t+4h, base_t+4h+1)
        unsigned u0 = pkbf(p[0],  p[1]),  u1 = pkbf(p[2],  p[3]);
        unsigned u2 = pkbf(p[4],  p[5]),  u3 = pkbf(p[6],  p[7]);
        unsigned u4 = pkbf(p[8],  p[9]),  u5 = pkbf(p[10], p[11]);
        unsigned u6 = pkbf(p[12], p[13]), u7 = pkbf(p[14], p[15]);
        const unsigned x0 = __shfl_xor(u0, 32, 64), x1 = __shfl_xor(u1, 32, 64);
        const unsigned x2 = __shfl_xor(u2, 32, 64), x3 = __shfl_xor(u3, 32, 64);
        const unsigned x4 = __shfl_xor(u4, 32, 64), x5 = __shfl_xor(u5, 32, 64);
        const unsigned x6 = __shfl_xor(u6, 32, 64), x7 = __shfl_xor(u7, 32, 64);
        // B-frag (P^T): lane holds keys kh*16 + h*8 + j, query l5
        int4v pb0 = (int4v){ (int)(h ? x2 : u0), (int)(h ? x3 : u1),
                             (int)(h ? u2 : x0), (int)(h ? u3 : x1) };
        int4v pb1 = (int4v){ (int)(h ? x6 : u4), (int)(h ? x7 : u5),
                             (int)(h ? u6 : x4), (int)(h ? u7 : x5) };
        const short8 pbf0 = __builtin_bit_cast(short8, pb0);
        const short8 pbf1 = __builtin_bit_cast(short8, pb1);

        // out^T[d][q] += V^T . P^T   (2 d-halves x 2 k-halves)
        {
            const short8 va00 = *(const short8*)&Vs[l5][h * 8];
            const short8 va01 = *(const short8*)&Vs[l5][16 + h * 8];
            oacc0 = __builtin_amdgcn_mfma_f32_32x32x16_bf16(va00, pbf0, oacc0, 0, 0, 0);
            oacc0 = __builtin_amdgcn_mfma_f32_32x32x16_bf16(va01, pbf1, oacc0, 0, 0, 0);
            const short8 va10 = *(const short8*)&Vs[32 + l5][h * 8];
            const short8 va11 = *(const short8*)&Vs[32 + l5][16 + h * 8];
            oacc1 = __builtin_amdgcn_mfma_f32_32x32x16_bf16(va10, pbf0, oacc1, 0, 0, 0);
            oacc1 = __builtin_amdgcn_mfma_f32_32x32x16_bf16(va11, pbf1, oacc1, 0, 0, 0);
        }
    }

    // epilogue: LDS transpose (per-wave region), coalesced Part write
    __syncthreads();
    float (*epi)[68] = (float(*)[68])(smem + wave * 8704);   // [32 q][64 d]
#pragma unroll
    for (int r = 0; r < 16; ++r) {
        const int d = (r & 3) + 8 * (r >> 2) + 4 * h;
        epi[l5][d]      = oacc0[r];
        epi[l5][32 + d] = oacc1[r];
    }
    __builtin_amdgcn_s_waitcnt(0);   // lgkm drain within wave (compiler also handles)
#pragma unroll
    for (int pass = 0; pass < 8; ++pass) {
        const int row = pass * 4 + (lane >> 4);
        const int col = (lane & 15) * 4;
        const float4 v = *(const float4*)&epi[row][col];
        *(float4*)&Part[((size_t)bh * SEQ + q0w + row) * HD + col] = v;
    }
    if (lane < 32) {
        float2 ml; ml.x = m; ml.y = l;
        *(float2*)&ML[((half * 32 + bh) * SEQ + q0w + lane) * 2] = ml;
    }
}

// ---------------------------------------------------------------------------
// Merge the two seq-halves: ctx = (w0*P0 + w1*P1) / (w0*l0 + w1*l1)
// One thread per float4 group. 4096 blocks x 256.
// ---------------------------------------------------------------------------
__global__ __launch_bounds__(256) void attn_merge(
    const float* __restrict__ Part0, const float* __restrict__ Part1,
    const float* __restrict__ ML, float* __restrict__ ctx)
{
    const int idx = blockIdx.x * 256 + threadIdx.x;   // 0..2^20-1
    const int g  = idx & 15;
    const int q  = (idx >> 4) & 2047;
    const int bh = idx >> 15;
    const int b  = bh >> 4, h = bh & 15;

    const float2 ml0 = *(const float2*)&ML[(bh * SEQ + q) * 2];
    const float2 ml1 = *(const float2*)&ML[((32 + bh) * SEQ + q) * 2];
    const float M  = fmaxf(ml0.x, ml1.x);
    const float w0 = exp2f(ml0.x - M), w1 = exp2f(ml1.x - M);
    const float inv = 1.0f / (ml0.y * w0 + ml1.y * w1);

    const size_t off = ((size_t)bh * SEQ + q) * HD + g * 4;
    const float4 p0 = *(const float4*)&Part0[off];
    const float4 p1 = *(const float4*)&Part1[off];
    float4 o;
    o.x = (p0.x * w0 + p1.x * w1) * inv;
    o.y = (p0.y * w0 + p1.y * w1) * inv;
    o.z = (p0.z * w0 + p1.z * w1) * inv;
    o.w = (p0.w * w0 + p1.w * w1) * inv;
    *(float4*)&ctx[((size_t)(b * SEQ + q)) * D_MODEL + h * HD + g * 4] = o;
}

// ---------------------------------------------------------------------------
// Output GEMM (split-bf16): out = ctx @ Wout + bout, fp32 in/out.
// ---------------------------------------------------------------------------
__global__ __launch_bounds__(256) void out_gemm_split(
    const float* __restrict__ A,
    const short* __restrict__ Bh, const short* __restrict__ Bl,
    const float* __restrict__ bias, float* __restrict__ out)
{
    __shared__ short Ah[64][40], Al[64][40];
    __shared__ short Bhs[64][40], Bls[64][40];

    const int tid  = threadIdx.x;
    const int wave = tid >> 6, lane = tid & 63;
    const int q4 = lane >> 4, l16 = lane & 15;
    const int m0 = blockIdx.y * 64;
    const int n0 = blockIdx.x * 64;
    const int sr = tid >> 2;
    const int sc = (tid & 3) * 8;

    f32x4 acc[4];
#pragma unroll
    for (int c = 0; c < 4; ++c) acc[c] = (f32x4){0.f, 0.f, 0.f, 0.f};

    for (int kt = 0; kt < D_MODEL; kt += 32) {
        const float8 av = *(const float8*)&A[(m0 + sr) * D_MODEL + kt + sc];
        short8 ah, al;
#pragma unroll
        for (int i = 0; i < 8; ++i) {
            ah[i] = f2bf(av[i]);
            al[i] = f2bf(av[i] - bf2f(ah[i]));
        }
        *(short8*)&Ah[sr][sc]  = ah;
        *(short8*)&Al[sr][sc]  = al;
        *(short8*)&Bhs[sr][sc] = *(const short8*)&Bh[(n0 + sr) * D_MODEL + kt + sc];
        *(short8*)&Bls[sr][sc] = *(const short8*)&Bl[(n0 + sr) * D_MODEL + kt + sc];
        __syncthreads();
        const short8 afh = *(const short8*)&Ah[wave * 16 + l16][q4 * 8];
        const short8 afl = *(const short8*)&Al[wave * 16 + l16][q4 * 8];
#pragma unroll
        for (int c = 0; c < 4; ++c) {
            const short8 bfh = *(const short8*)&Bhs[c * 16 + l16][q4 * 8];
            const short8 bfl = *(const short8*)&Bls[c * 16 + l16][q4 * 8];
            acc[c] = __builtin_amdgcn_mfma_f32_16x16x32_bf16(afh, bfh, acc[c], 0, 0, 0);
            acc[c] = __builtin_amdgcn_mfma_f32_16x16x32_bf16(afh, bfl, acc[c], 0, 0, 0);
            acc[c] = __builtin_amdgcn_mfma_f32_16x16x32_bf16(afl, bfh, acc[c], 0, 0, 0);
        }
        __syncthreads();
    }

    const int mbase = m0 + wave * 16 + q4 * 4;
#pragma unroll
    for (int c = 0; c < 4; ++c) {
        const int n = n0 + c * 16 + l16;
        const float bv = bias[n];
#pragma unroll
        for (int r = 0; r < 4; ++r)
            out[(mbase + r) * D_MODEL + n] = acc[c][r] + bv;
    }
}

// ---------------------------------------------------------------------------
extern "C" void kernel_launch(void* const* d_in, const int* in_sizes, int n_in,
                              void* d_out, int out_size, void* d_ws, size_t ws_size,
                              hipStream_t stream)
{
    const float* x    = (const float*)d_in[0];
    const float* Wqkv = (const float*)d_in[1];
    const float* bqkv = (const float*)d_in[2];
    const float* Wout = (const float*)d_in[3];
    const float* bout = (const float*)d_in[4];
    float* out = (float*)d_out;

    char* ws = (char*)d_ws;
    short* Qb    = (short*)(ws);                  //  8 MB  [32][2048][64] bf16 (pre-scaled)
    short* Kb    = (short*)(ws +  8*MB);          //  8 MB
    short* Vtb   = (short*)(ws + 16*MB);          //  8 MB  [32][64][2048]
    float* ctx   = (float*)(ws + 24*MB);          // 16 MB
    short* Woh   = (short*)(ws + 40*MB);          //  2 MB
    short* Wol   = (short*)(ws + 42*MB);          //  2 MB
    float* ML    = (float*)(ws + 44*MB);          //  1 MB  [2][32][2048]x(m,l)
    float* Part0 = (float*)(ws + 45*MB);          // 16 MB
    float* Part1 = (float*)(ws + 61*MB);          // 16 MB  (end 77 MB)
    // Wqkv^T splits alias Part0 (dead before attention runs)
    short* Wh    = (short*)(ws + 45*MB);          //  6 MB
    short* Wl    = (short*)(ws + 51*MB);          //  6 MB

    transpose_split<<<dim3(96, 32), dim3(32, 8), 0, stream>>>(Wqkv, Wh, Wl, D_MODEL, N3);
    transpose_split<<<dim3(32, 32), dim3(32, 8), 0, stream>>>(Wout, Woh, Wol, D_MODEL, D_MODEL);
    qkv_gemm_split<<<dim3(48, 64), 256, 0, stream>>>(x, Wh, Wl, bqkv, Qb, Kb, Vtb);
    attn_tscore<<<dim3(32, 16, 2), 256, 0, stream>>>(Qb, Kb, Vtb, Part0, Part1, ML);
    attn_merge<<<4096, 256, 0, stream>>>(Part0, Part1, ML, ctx);
    out_gemm_split<<<dim3(16, 64), 256, 0, stream>>>(ctx, Woh, Wol, bout, out);
}

// Round 7
// 325.079 us; speedup vs baseline: 7.7351x; 1.0754x over previous
//
#include <hip/hip_runtime.h>

// ---------------------------------------------------------------------------
// MultiHeadAttention, fp32 in/out.
// Projections: split-bf16 (hi+lo, 3 products) 128x128-tile MFMA GEMMs with
//   global_load_lds 16B staging (m97 ladder structure).
// Attention: transposed-score flash (S^T = K.Q^T, 32x32x16 MFMA),
//   lane-scalar online softmax, seq-split-2 + merge.
// ---------------------------------------------------------------------------

typedef __attribute__((ext_vector_type(8)))  short short8;
typedef __attribute__((ext_vector_type(8)))  float float8;
typedef __attribute__((ext_vector_type(4)))  float f32x4;
typedef __attribute__((ext_vector_type(16))) float f32x16;
typedef __attribute__((ext_vector_type(4)))  int   int4v;

#define D_MODEL 1024
#define NHEAD   16
#define HD      64
#define SEQ     2048
#define N3      (3*D_MODEL)
#define MB      (1024*1024)

static __device__ __forceinline__ float bf2f(short s) {
    unsigned u = ((unsigned)(unsigned short)s) << 16;
    return __builtin_bit_cast(float, u);
}
static __device__ __forceinline__ short f2bf(float f) {
    unsigned u = __builtin_bit_cast(unsigned, f);
    u = (u + 0x7fff + ((u >> 16) & 1)) >> 16;   // RNE
    return (short)u;
}
static __device__ __forceinline__ unsigned pkbf(float a, float b) {
    unsigned ua = __builtin_bit_cast(unsigned, a);
    ua = (ua + 0x7fff + ((ua >> 16) & 1)) >> 16;
    unsigned ub = __builtin_bit_cast(unsigned, b);
    ub = (ub + 0x7fff + ((ub >> 16) & 1)) & 0xffff0000u;
    return ua | ub;
}
// async global->LDS, 16B per lane (dest must be wave-uniform base + lane*16)
static __device__ __forceinline__ void gl16(const short* g, short* l) {
    __builtin_amdgcn_global_load_lds(
        (const __attribute__((address_space(1))) unsigned int*)g,
        (__attribute__((address_space(3))) unsigned int*)l, 16, 0, 0);
}

// ---------------------------------------------------------------------------
// Split x fp32 -> bf16 hi/lo (no transpose).
// ---------------------------------------------------------------------------
__global__ __launch_bounds__(256) void split_x(
    const float* __restrict__ x, short* __restrict__ xh, short* __restrict__ xl)
{
    const int i = (blockIdx.x * 256 + threadIdx.x) * 8;
    const float8 v = *(const float8*)&x[i];
    short8 h, l;
#pragma unroll
    for (int j = 0; j < 8; ++j) {
        h[j] = f2bf(v[j]);
        l[j] = f2bf(v[j] - bf2f(h[j]));
    }
    *(short8*)&xh[i] = h;
    *(short8*)&xl[i] = l;
}

// ---------------------------------------------------------------------------
// Transpose fp32 [K][N] -> split bf16 hi/lo, each [N][K].
// ---------------------------------------------------------------------------
__global__ __launch_bounds__(256) void transpose_split(
    const float* __restrict__ in, short* __restrict__ hi, short* __restrict__ lo,
    int K, int N)
{
    __shared__ float tile[32][33];
    const int n0 = blockIdx.x * 32;
    const int k0 = blockIdx.y * 32;
    const int tx = threadIdx.x, ty = threadIdx.y;
#pragma unroll
    for (int i = 0; i < 4; ++i)
        tile[ty + 8*i][tx] = in[(k0 + ty + 8*i) * N + (n0 + tx)];
    __syncthreads();
#pragma unroll
    for (int i = 0; i < 4; ++i) {
        const float v  = tile[tx][ty + 8*i];
        const short vh = f2bf(v);
        const short vl = f2bf(v - bf2f(vh));
        const int idx  = (n0 + ty + 8*i) * K + (k0 + tx);
        hi[idx] = vh;
        lo[idx] = vl;
    }
}

// ---------------------------------------------------------------------------
// QKV GEMM, 128x128 tile, BK=32, global_load_lds staging, split-bf16.
// C[4096,3072] = X @ Wqkv + b. Scatter: Q (pre-scaled), K, Vt (bf16).
// ---------------------------------------------------------------------------
__global__ __launch_bounds__(256) void qkv_gemm128(
    const short* __restrict__ Xh, const short* __restrict__ Xl,
    const short* __restrict__ Bh, const short* __restrict__ Bl,
    const float* __restrict__ bias,
    short* __restrict__ Qo, short* __restrict__ Ko, short* __restrict__ Vt)
{
    __shared__ short XhS[128*32], XlS[128*32], BhS[128*32], BlS[128*32];

    const int tid  = threadIdx.x;
    const int wave = tid >> 6, lane = tid & 63;
    const int q4 = lane >> 4, l16 = lane & 15;
    const int m0 = blockIdx.y * 128, n0 = blockIdx.x * 128;
    const int rw = (wave & 1) * 64, cw = (wave >> 1) * 64;
    const int trow = tid >> 2;          // 0..63
    const int tcol = (tid & 3) * 8;     // element col

    f32x4 acc[4][4];
#pragma unroll
    for (int i = 0; i < 4; ++i)
#pragma unroll
        for (int j = 0; j < 4; ++j) acc[i][j] = (f32x4){0.f, 0.f, 0.f, 0.f};

    for (int kt = 0; kt < D_MODEL; kt += 32) {
        gl16(&Xh[(m0 + trow) * D_MODEL + kt + tcol],      XhS + tid * 8);
        gl16(&Xh[(m0 + 64 + trow) * D_MODEL + kt + tcol], XhS + 2048 + tid * 8);
        gl16(&Xl[(m0 + trow) * D_MODEL + kt + tcol],      XlS + tid * 8);
        gl16(&Xl[(m0 + 64 + trow) * D_MODEL + kt + tcol], XlS + 2048 + tid * 8);
        gl16(&Bh[(n0 + trow) * D_MODEL + kt + tcol],      BhS + tid * 8);
        gl16(&Bh[(n0 + 64 + trow) * D_MODEL + kt + tcol], BhS + 2048 + tid * 8);
        gl16(&Bl[(n0 + trow) * D_MODEL + kt + tcol],      BlS + tid * 8);
        gl16(&Bl[(n0 + 64 + trow) * D_MODEL + kt + tcol], BlS + 2048 + tid * 8);
        __syncthreads();

        short8 ah[4], al[4], bh[4], bl[4];
#pragma unroll
        for (int t = 0; t < 4; ++t) {
            ah[t] = *(const short8*)&XhS[(rw + t * 16 + l16) * 32 + q4 * 8];
            al[t] = *(const short8*)&XlS[(rw + t * 16 + l16) * 32 + q4 * 8];
            bh[t] = *(const short8*)&BhS[(cw + t * 16 + l16) * 32 + q4 * 8];
            bl[t] = *(const short8*)&BlS[(cw + t * 16 + l16) * 32 + q4 * 8];
        }
#pragma unroll
        for (int ti = 0; ti < 4; ++ti)
#pragma unroll
            for (int tj = 0; tj < 4; ++tj) {
                acc[ti][tj] = __builtin_amdgcn_mfma_f32_16x16x32_bf16(ah[ti], bh[tj], acc[ti][tj], 0, 0, 0);
                acc[ti][tj] = __builtin_amdgcn_mfma_f32_16x16x32_bf16(ah[ti], bl[tj], acc[ti][tj], 0, 0, 0);
                acc[ti][tj] = __builtin_amdgcn_mfma_f32_16x16x32_bf16(al[ti], bh[tj], acc[ti][tj], 0, 0, 0);
            }
        __syncthreads();
    }

    const float SCALE_Q = 0.125f * 1.4426950408889634f;
#pragma unroll
    for (int tj = 0; tj < 4; ++tj) {
        const int n = n0 + cw + tj * 16 + l16;    // 0..3071
        const int h = n / 192;
        const int jj = n % 192;
        const float bv = bias[n];
#pragma unroll
        for (int ti = 0; ti < 4; ++ti) {
            const int mb = m0 + rw + ti * 16 + q4 * 4;
#pragma unroll
            for (int r = 0; r < 4; ++r) {
                const int m = mb + r;
                const int b = m >> 11;
                const int s = m & 2047;
                const float v = acc[ti][tj][r] + bv;
                const int bh_ = b * NHEAD + h;
                if (jj < 64)       Qo[(bh_ * SEQ + s) * HD + jj] = f2bf(v * SCALE_Q);
                else if (jj < 128) Ko[(bh_ * SEQ + s) * HD + (jj - 64)] = f2bf(v);
                else               Vt[(bh_ * HD + (jj - 128)) * SEQ + s] = f2bf(v);
            }
        }
    }
}

// ---------------------------------------------------------------------------
// Transposed-score flash attention, seq-split-2 (unchanged from R6).
// ---------------------------------------------------------------------------
__global__ __launch_bounds__(256, 4) void attn_tscore(
    const short* __restrict__ Q, const short* __restrict__ K,
    const short* __restrict__ Vt,
    float* __restrict__ Part0, float* __restrict__ Part1,
    float* __restrict__ ML)
{
    __shared__ __attribute__((aligned(16))) char smem[34816];
    short (*Ks)[72] = (short(*)[72])smem;                 // [32 key][64 d]
    short (*Vs)[40] = (short(*)[40])(smem + 4608);        // [64 d][32 key]

    const int bh   = blockIdx.x;
    const int qb   = blockIdx.y;
    const int half = blockIdx.z;
    const int kbase0 = half * 1024;

    const short* Qp  = Q  + bh * SEQ * HD;
    const short* Kp  = K  + bh * SEQ * HD;
    const short* Vtp = Vt + bh * HD * SEQ;
    float* Part = half ? Part1 : Part0;

    const int tid  = threadIdx.x;
    const int wave = tid >> 6, lane = tid & 63;
    const int l5 = lane & 31, h = lane >> 5;
    const int q0w = qb * 128 + wave * 32;

    short8 qf[4];
#pragma unroll
    for (int c = 0; c < 4; ++c)
        qf[c] = *(const short8*)&Qp[(q0w + l5) * HD + c * 16 + h * 8];

    f32x16 oacc0 = (f32x16)(0.f), oacc1 = (f32x16)(0.f);
    float m = -1.0e30f, l = 0.f;

    const int sKr = tid >> 3, sKc = (tid & 7) * 8;
    const int sVr = tid >> 2, sVc = (tid & 3) * 8;

    for (int kc = 0; kc < 32; ++kc) {
        const int kbase = kbase0 + kc * 32;
        __syncthreads();
        *(short8*)&Ks[sKr][sKc] = *(const short8*)&Kp[(kbase + sKr) * HD + sKc];
        *(short8*)&Vs[sVr][sVc] = *(const short8*)&Vtp[sVr * SEQ + kbase + sVc];
        __syncthreads();

        f32x16 sacc = (f32x16)(0.f);
#pragma unroll
        for (int c = 0; c < 4; ++c) {
            const short8 ka = *(const short8*)&Ks[l5][c * 16 + h * 8];
            sacc = __builtin_amdgcn_mfma_f32_32x32x16_bf16(ka, qf[c], sacc, 0, 0, 0);
        }

        float a0 = fmaxf(sacc[0], sacc[8]),  a1 = fmaxf(sacc[1], sacc[9]);
        float a2 = fmaxf(sacc[2], sacc[10]), a3 = fmaxf(sacc[3], sacc[11]);
        float a4 = fmaxf(sacc[4], sacc[12]), a5 = fmaxf(sacc[5], sacc[13]);
        float a6 = fmaxf(sacc[6], sacc[14]), a7 = fmaxf(sacc[7], sacc[15]);
        a0 = fmaxf(a0, a4); a1 = fmaxf(a1, a5); a2 = fmaxf(a2, a6); a3 = fmaxf(a3, a7);
        a0 = fmaxf(fmaxf(a0, a1), fmaxf(a2, a3));
        a0 = fmaxf(a0, __shfl_xor(a0, 32, 64));
        const float mnew  = fmaxf(m, a0);
        const float alpha = exp2f(m - mnew);

        float p[16];
#pragma unroll
        for (int i = 0; i < 16; ++i) p[i] = exp2f(sacc[i] - mnew);

        float s0 = p[0]+p[8], s1 = p[1]+p[9], s2 = p[2]+p[10], s3 = p[3]+p[11];
        float s4 = p[4]+p[12], s5 = p[5]+p[13], s6 = p[6]+p[14], s7 = p[7]+p[15];
        s0 += s4; s1 += s5; s2 += s6; s3 += s7;
        float rs = (s0 + s1) + (s2 + s3);
        rs += __shfl_xor(rs, 32, 64);
        l = l * alpha + rs;
        m = mnew;

#pragma unroll
        for (int i = 0; i < 16; ++i) { oacc0[i] *= alpha; oacc1[i] *= alpha; }

        unsigned u0 = pkbf(p[0],  p[1]),  u1 = pkbf(p[2],  p[3]);
        unsigned u2 = pkbf(p[4],  p[5]),  u3 = pkbf(p[6],  p[7]);
        unsigned u4 = pkbf(p[8],  p[9]),  u5 = pkbf(p[10], p[11]);
        unsigned u6 = pkbf(p[12], p[13]), u7 = pkbf(p[14], p[15]);
        const unsigned x0 = __shfl_xor(u0, 32, 64), x1 = __shfl_xor(u1, 32, 64);
        const unsigned x2 = __shfl_xor(u2, 32, 64), x3 = __shfl_xor(u3, 32, 64);
        const unsigned x4 = __shfl_xor(u4, 32, 64), x5 = __shfl_xor(u5, 32, 64);
        const unsigned x6 = __shfl_xor(u6, 32, 64), x7 = __shfl_xor(u7, 32, 64);
        int4v pb0 = (int4v){ (int)(h ? x2 : u0), (int)(h ? x3 : u1),
                             (int)(h ? u2 : x0), (int)(h ? u3 : x1) };
        int4v pb1 = (int4v){ (int)(h ? x6 : u4), (int)(h ? x7 : u5),
                             (int)(h ? u6 : x4), (int)(h ? u7 : x5) };
        const short8 pbf0 = __builtin_bit_cast(short8, pb0);
        const short8 pbf1 = __builtin_bit_cast(short8, pb1);

        {
            const short8 va00 = *(const short8*)&Vs[l5][h * 8];
            const short8 va01 = *(const short8*)&Vs[l5][16 + h * 8];
            oacc0 = __builtin_amdgcn_mfma_f32_32x32x16_bf16(va00, pbf0, oacc0, 0, 0, 0);
            oacc0 = __builtin_amdgcn_mfma_f32_32x32x16_bf16(va01, pbf1, oacc0, 0, 0, 0);
            const short8 va10 = *(const short8*)&Vs[32 + l5][h * 8];
            const short8 va11 = *(const short8*)&Vs[32 + l5][16 + h * 8];
            oacc1 = __builtin_amdgcn_mfma_f32_32x32x16_bf16(va10, pbf0, oacc1, 0, 0, 0);
            oacc1 = __builtin_amdgcn_mfma_f32_32x32x16_bf16(va11, pbf1, oacc1, 0, 0, 0);
        }
    }

    __syncthreads();
    float (*epi)[68] = (float(*)[68])(smem + wave * 8704);
#pragma unroll
    for (int r = 0; r < 16; ++r) {
        const int d = (r & 3) + 8 * (r >> 2) + 4 * h;
        epi[l5][d]      = oacc0[r];
        epi[l5][32 + d] = oacc1[r];
    }
    __builtin_amdgcn_s_waitcnt(0);
#pragma unroll
    for (int pass = 0; pass < 8; ++pass) {
        const int row = pass * 4 + (lane >> 4);
        const int col = (lane & 15) * 4;
        const float4 v = *(const float4*)&epi[row][col];
        *(float4*)&Part[((size_t)bh * SEQ + q0w + row) * HD + col] = v;
    }
    if (lane < 32) {
        float2 ml; ml.x = m; ml.y = l;
        *(float2*)&ML[((half * 32 + bh) * SEQ + q0w + lane) * 2] = ml;
    }
}

// ---------------------------------------------------------------------------
// Merge halves; emit split-bf16 ctx (hi/lo) in [b*S+q][h*64+d] layout.
// ---------------------------------------------------------------------------
__global__ __launch_bounds__(256) void attn_merge(
    const float* __restrict__ Part0, const float* __restrict__ Part1,
    const float* __restrict__ ML,
    short* __restrict__ Ch, short* __restrict__ Cl)
{
    const int idx = blockIdx.x * 256 + threadIdx.x;   // 0..2^20-1
    const int g  = idx & 15;
    const int q  = (idx >> 4) & 2047;
    const int bh = idx >> 15;
    const int b  = bh >> 4, h = bh & 15;

    const float2 ml0 = *(const float2*)&ML[(bh * SEQ + q) * 2];
    const float2 ml1 = *(const float2*)&ML[((32 + bh) * SEQ + q) * 2];
    const float M  = fmaxf(ml0.x, ml1.x);
    const float w0 = exp2f(ml0.x - M), w1 = exp2f(ml1.x - M);
    const float inv = 1.0f / (ml0.y * w0 + ml1.y * w1);

    const size_t off = ((size_t)bh * SEQ + q) * HD + g * 4;
    const float4 p0 = *(const float4*)&Part0[off];
    const float4 p1 = *(const float4*)&Part1[off];
    float o[4];
    o[0] = (p0.x * w0 + p1.x * w1) * inv;
    o[1] = (p0.y * w0 + p1.y * w1) * inv;
    o[2] = (p0.z * w0 + p1.z * w1) * inv;
    o[3] = (p0.w * w0 + p1.w * w1) * inv;

    const size_t co = ((size_t)(b * SEQ + q)) * D_MODEL + h * HD + g * 4;
    short4 hh, ll;
    short* hp = (short*)&hh; short* lp = (short*)&ll;
#pragma unroll
    for (int i = 0; i < 4; ++i) {
        hp[i] = f2bf(o[i]);
        lp[i] = f2bf(o[i] - bf2f(hp[i]));
    }
    *(short4*)&Ch[co] = hh;
    *(short4*)&Cl[co] = ll;
}

// ---------------------------------------------------------------------------
// Output GEMM, 128x128 tile, global_load_lds staging, split-bf16.
// out[4096,1024] = ctx @ Wout + bout (fp32 out).
// ---------------------------------------------------------------------------
__global__ __launch_bounds__(256) void out_gemm128(
    const short* __restrict__ Ah, const short* __restrict__ Al,
    const short* __restrict__ Bh, const short* __restrict__ Bl,
    const float* __restrict__ bias, float* __restrict__ out)
{
    __shared__ short AhS[128*32], AlS[128*32], BhS[128*32], BlS[128*32];

    const int tid  = threadIdx.x;
    const int wave = tid >> 6, lane = tid & 63;
    const int q4 = lane >> 4, l16 = lane & 15;
    const int m0 = blockIdx.y * 128, n0 = blockIdx.x * 128;
    const int rw = (wave & 1) * 64, cw = (wave >> 1) * 64;
    const int trow = tid >> 2;
    const int tcol = (tid & 3) * 8;

    f32x4 acc[4][4];
#pragma unroll
    for (int i = 0; i < 4; ++i)
#pragma unroll
        for (int j = 0; j < 4; ++j) acc[i][j] = (f32x4){0.f, 0.f, 0.f, 0.f};

    for (int kt = 0; kt < D_MODEL; kt += 32) {
        gl16(&Ah[(m0 + trow) * D_MODEL + kt + tcol],      AhS + tid * 8);
        gl16(&Ah[(m0 + 64 + trow) * D_MODEL + kt + tcol], AhS + 2048 + tid * 8);
        gl16(&Al[(m0 + trow) * D_MODEL + kt + tcol],      AlS + tid * 8);
        gl16(&Al[(m0 + 64 + trow) * D_MODEL + kt + tcol], AlS + 2048 + tid * 8);
        gl16(&Bh[(n0 + trow) * D_MODEL + kt + tcol],      BhS + tid * 8);
        gl16(&Bh[(n0 + 64 + trow) * D_MODEL + kt + tcol], BhS + 2048 + tid * 8);
        gl16(&Bl[(n0 + trow) * D_MODEL + kt + tcol],      BlS + tid * 8);
        gl16(&Bl[(n0 + 64 + trow) * D_MODEL + kt + tcol], BlS + 2048 + tid * 8);
        __syncthreads();

        short8 ah[4], al[4], bh[4], bl[4];
#pragma unroll
        for (int t = 0; t < 4; ++t) {
            ah[t] = *(const short8*)&AhS[(rw + t * 16 + l16) * 32 + q4 * 8];
            al[t] = *(const short8*)&AlS[(rw + t * 16 + l16) * 32 + q4 * 8];
            bh[t] = *(const short8*)&BhS[(cw + t * 16 + l16) * 32 + q4 * 8];
            bl[t] = *(const short8*)&BlS[(cw + t * 16 + l16) * 32 + q4 * 8];
        }
#pragma unroll
        for (int ti = 0; ti < 4; ++ti)
#pragma unroll
            for (int tj = 0; tj < 4; ++tj) {
                acc[ti][tj] = __builtin_amdgcn_mfma_f32_16x16x32_bf16(ah[ti], bh[tj], acc[ti][tj], 0, 0, 0);
                acc[ti][tj] = __builtin_amdgcn_mfma_f32_16x16x32_bf16(ah[ti], bl[tj], acc[ti][tj], 0, 0, 0);
                acc[ti][tj] = __builtin_amdgcn_mfma_f32_16x16x32_bf16(al[ti], bh[tj], acc[ti][tj], 0, 0, 0);
            }
        __syncthreads();
    }

#pragma unroll
    for (int tj = 0; tj < 4; ++tj) {
        const int n = n0 + cw + tj * 16 + l16;
        const float bv = bias[n];
#pragma unroll
        for (int ti = 0; ti < 4; ++ti) {
            const int mb = m0 + rw + ti * 16 + q4 * 4;
#pragma unroll
            for (int r = 0; r < 4; ++r)
                out[(mb + r) * D_MODEL + n] = acc[ti][tj][r] + bv;
        }
    }
}

// ---------------------------------------------------------------------------
extern "C" void kernel_launch(void* const* d_in, const int* in_sizes, int n_in,
                              void* d_out, int out_size, void* d_ws, size_t ws_size,
                              hipStream_t stream)
{
    const float* x    = (const float*)d_in[0];
    const float* Wqkv = (const float*)d_in[1];
    const float* bqkv = (const float*)d_in[2];
    const float* Wout = (const float*)d_in[3];
    const float* bout = (const float*)d_in[4];
    float* out = (float*)d_out;

    char* ws = (char*)d_ws;
    short* Qb    = (short*)(ws);                  //  8 MB [32][2048][64] (pre-scaled)
    short* Kb    = (short*)(ws +  8*MB);          //  8 MB
    short* Vtb   = (short*)(ws + 16*MB);          //  8 MB [32][64][2048]
    short* Woh   = (short*)(ws + 24*MB);          //  2 MB Wout^T hi
    short* Wol   = (short*)(ws + 26*MB);          //  2 MB Wout^T lo
    float* ML    = (float*)(ws + 28*MB);          //  1 MB
    short* Ch    = (short*)(ws + 29*MB);          //  8 MB ctx hi
    short* Cl    = (short*)(ws + 37*MB);          //  8 MB ctx lo
    float* Part0 = (float*)(ws + 45*MB);          // 16 MB
    float* Part1 = (float*)(ws + 61*MB);          // 16 MB (end 77 MB)
    // aliases (dead before attention writes Part0/Part1):
    short* Xh    = (short*)(ws + 45*MB);          //  8 MB x hi  (in Part0)
    short* Xl    = (short*)(ws + 53*MB);          //  8 MB x lo  (in Part0)
    short* Wh    = (short*)(ws + 61*MB);          //  6 MB Wqkv^T hi (in Part1)
    short* Wl    = (short*)(ws + 67*MB);          //  6 MB Wqkv^T lo (in Part1)

    transpose_split<<<dim3(96, 32), dim3(32, 8), 0, stream>>>(Wqkv, Wh, Wl, D_MODEL, N3);
    transpose_split<<<dim3(32, 32), dim3(32, 8), 0, stream>>>(Wout, Woh, Wol, D_MODEL, D_MODEL);
    split_x<<<2048, 256, 0, stream>>>(x, Xh, Xl);
    qkv_gemm128<<<dim3(24, 32), 256, 0, stream>>>(Xh, Xl, Wh, Wl, bqkv, Qb, Kb, Vtb);
    attn_tscore<<<dim3(32, 16, 2), 256, 0, stream>>>(Qb, Kb, Vtb, Part0, Part1, ML);
    attn_merge<<<4096, 256, 0, stream>>>(Part0, Part1, ML, Ch, Cl);
    out_gemm128<<<dim3(8, 32), 256, 0, stream>>>(Ch, Cl, Woh, Wol, bout, out);
}

// Round 8
// 316.166 us; speedup vs baseline: 7.9531x; 1.0282x over previous
//
#include <hip/hip_runtime.h>

// ---------------------------------------------------------------------------
// MultiHeadAttention, fp32 in/out. 4-kernel pipeline:
//   prep      : Wqkv^T/Wout^T transpose+split-bf16, x split-bf16 (fused)
//   qkv_gemm  : 128x128 split-bf16 MFMA, global_load_lds; scatters Q,K,Vt bf16
//   attn      : transposed-score flash (S^T=K.Q^T, 32x32x16), full-seq,
//               lane-scalar softmax, writes split-bf16 ctx directly
//   out_gemm  : 128x128 split-bf16 MFMA -> fp32 out
// ---------------------------------------------------------------------------

typedef __attribute__((ext_vector_type(8)))  short short8;
typedef __attribute__((ext_vector_type(4)))  short short4v;
typedef __attribute__((ext_vector_type(8)))  float float8;
typedef __attribute__((ext_vector_type(4)))  float f32x4;
typedef __attribute__((ext_vector_type(16))) float f32x16;
typedef __attribute__((ext_vector_type(4)))  int   int4v;

#define D_MODEL 1024
#define NHEAD   16
#define HD      64
#define SEQ     2048
#define N3      (3*D_MODEL)
#define MB      (1024*1024)

static __device__ __forceinline__ float bf2f(short s) {
    unsigned u = ((unsigned)(unsigned short)s) << 16;
    return __builtin_bit_cast(float, u);
}
static __device__ __forceinline__ short f2bf(float f) {
    unsigned u = __builtin_bit_cast(unsigned, f);
    u = (u + 0x7fff + ((u >> 16) & 1)) >> 16;   // RNE
    return (short)u;
}
static __device__ __forceinline__ unsigned pkbf(float a, float b) {
    unsigned ua = __builtin_bit_cast(unsigned, a);
    ua = (ua + 0x7fff + ((ua >> 16) & 1)) >> 16;
    unsigned ub = __builtin_bit_cast(unsigned, b);
    ub = (ub + 0x7fff + ((ub >> 16) & 1)) & 0xffff0000u;
    return ua | ub;
}
static __device__ __forceinline__ void gl16(const short* g, short* l) {
    __builtin_amdgcn_global_load_lds(
        (const __attribute__((address_space(1))) unsigned int*)g,
        (__attribute__((address_space(3))) unsigned int*)l, 16, 0, 0);
}

// ---------------------------------------------------------------------------
// prep: blocks [0,2048) split x; [2048,5120) transpose-split Wqkv;
//       [5120,6144) transpose-split Wout.
// ---------------------------------------------------------------------------
__global__ __launch_bounds__(256) void prep(
    const float* __restrict__ x, const float* __restrict__ Wqkv,
    const float* __restrict__ Wout,
    short* __restrict__ Xh, short* __restrict__ Xl,
    short* __restrict__ Wh, short* __restrict__ Wl,
    short* __restrict__ Woh, short* __restrict__ Wol)
{
    __shared__ float tile[32][33];
    const int bid = blockIdx.x;
    const int tid = threadIdx.x;

    if (bid < 2048) {                        // ---- split x ----
        const int i = (bid * 256 + tid) * 8;
        const float8 v = *(const float8*)&x[i];
        short8 h, l;
#pragma unroll
        for (int j = 0; j < 8; ++j) {
            h[j] = f2bf(v[j]);
            l[j] = f2bf(v[j] - bf2f(h[j]));
        }
        *(short8*)&Xh[i] = h;
        *(short8*)&Xl[i] = l;
        return;
    }

    // ---- transpose + split a weight matrix ----
    const float* in; short *hi, *lo; int K, N, bx, by;
    if (bid < 5120) {
        const int b2 = bid - 2048;
        in = Wqkv; hi = Wh; lo = Wl; K = D_MODEL; N = N3;
        bx = b2 % 96; by = b2 / 96;
    } else {
        const int b3 = bid - 5120;
        in = Wout; hi = Woh; lo = Wol; K = D_MODEL; N = D_MODEL;
        bx = b3 & 31; by = b3 >> 5;
    }
    const int n0 = bx * 32, k0 = by * 32;
    const int tx = tid & 31, ty = tid >> 5;
#pragma unroll
    for (int i = 0; i < 4; ++i)
        tile[ty + 8*i][tx] = in[(k0 + ty + 8*i) * N + (n0 + tx)];
    __syncthreads();
#pragma unroll
    for (int i = 0; i < 4; ++i) {
        const float v  = tile[tx][ty + 8*i];
        const short vh = f2bf(v);
        const short vl = f2bf(v - bf2f(vh));
        const int idx  = (n0 + ty + 8*i) * K + (k0 + tx);
        hi[idx] = vh;
        lo[idx] = vl;
    }
}

// ---------------------------------------------------------------------------
// QKV GEMM, 128x128 tile, BK=32, global_load_lds, split-bf16 (3 products).
// Scatter: Q (pre-scaled by 0.125*log2e), K, Vt (short4-vectorized).
// ---------------------------------------------------------------------------
__global__ __launch_bounds__(256) void qkv_gemm128(
    const short* __restrict__ Xh, const short* __restrict__ Xl,
    const short* __restrict__ Bh, const short* __restrict__ Bl,
    const float* __restrict__ bias,
    short* __restrict__ Qo, short* __restrict__ Ko, short* __restrict__ Vt)
{
    __shared__ short XhS[128*32], XlS[128*32], BhS[128*32], BlS[128*32];

    const int tid  = threadIdx.x;
    const int wave = tid >> 6, lane = tid & 63;
    const int q4 = lane >> 4, l16 = lane & 15;
    const int m0 = blockIdx.y * 128, n0 = blockIdx.x * 128;
    const int rw = (wave & 1) * 64, cw = (wave >> 1) * 64;
    const int trow = tid >> 2;
    const int tcol = (tid & 3) * 8;

    f32x4 acc[4][4];
#pragma unroll
    for (int i = 0; i < 4; ++i)
#pragma unroll
        for (int j = 0; j < 4; ++j) acc[i][j] = (f32x4){0.f, 0.f, 0.f, 0.f};

    for (int kt = 0; kt < D_MODEL; kt += 32) {
        gl16(&Xh[(m0 + trow) * D_MODEL + kt + tcol],      XhS + tid * 8);
        gl16(&Xh[(m0 + 64 + trow) * D_MODEL + kt + tcol], XhS + 2048 + tid * 8);
        gl16(&Xl[(m0 + trow) * D_MODEL + kt + tcol],      XlS + tid * 8);
        gl16(&Xl[(m0 + 64 + trow) * D_MODEL + kt + tcol], XlS + 2048 + tid * 8);
        gl16(&Bh[(n0 + trow) * D_MODEL + kt + tcol],      BhS + tid * 8);
        gl16(&Bh[(n0 + 64 + trow) * D_MODEL + kt + tcol], BhS + 2048 + tid * 8);
        gl16(&Bl[(n0 + trow) * D_MODEL + kt + tcol],      BlS + tid * 8);
        gl16(&Bl[(n0 + 64 + trow) * D_MODEL + kt + tcol], BlS + 2048 + tid * 8);
        __syncthreads();

        short8 ah[4], al[4], bh[4], bl[4];
#pragma unroll
        for (int t = 0; t < 4; ++t) {
            ah[t] = *(const short8*)&XhS[(rw + t * 16 + l16) * 32 + q4 * 8];
            al[t] = *(const short8*)&XlS[(rw + t * 16 + l16) * 32 + q4 * 8];
            bh[t] = *(const short8*)&BhS[(cw + t * 16 + l16) * 32 + q4 * 8];
            bl[t] = *(const short8*)&BlS[(cw + t * 16 + l16) * 32 + q4 * 8];
        }
#pragma unroll
        for (int ti = 0; ti < 4; ++ti)
#pragma unroll
            for (int tj = 0; tj < 4; ++tj) {
                acc[ti][tj] = __builtin_amdgcn_mfma_f32_16x16x32_bf16(ah[ti], bh[tj], acc[ti][tj], 0, 0, 0);
                acc[ti][tj] = __builtin_amdgcn_mfma_f32_16x16x32_bf16(ah[ti], bl[tj], acc[ti][tj], 0, 0, 0);
                acc[ti][tj] = __builtin_amdgcn_mfma_f32_16x16x32_bf16(al[ti], bh[tj], acc[ti][tj], 0, 0, 0);
            }
        __syncthreads();
    }

    const float SCALE_Q = 0.125f * 1.4426950408889634f;
#pragma unroll
    for (int tj = 0; tj < 4; ++tj) {
        const int n = n0 + cw + tj * 16 + l16;    // 0..3071
        const int h = n / 192;
        const int jj = n % 192;
        const float bv = bias[n];
#pragma unroll
        for (int ti = 0; ti < 4; ++ti) {
            const int mb = m0 + rw + ti * 16 + q4 * 4;
            const int b = mb >> 11;
            const int s = mb & 2047;
            const int bh_ = b * NHEAD + h;
            if (jj >= 128) {                      // Vt: s is fast axis -> short4
                short4v v4;
#pragma unroll
                for (int r = 0; r < 4; ++r) v4[r] = f2bf(acc[ti][tj][r] + bv);
                *(short4v*)&Vt[(bh_ * HD + (jj - 128)) * SEQ + s] = v4;
            } else if (jj < 64) {
#pragma unroll
                for (int r = 0; r < 4; ++r)
                    Qo[(bh_ * SEQ + s + r) * HD + jj] = f2bf((acc[ti][tj][r] + bv) * SCALE_Q);
            } else {
#pragma unroll
                for (int r = 0; r < 4; ++r)
                    Ko[(bh_ * SEQ + s + r) * HD + (jj - 64)] = f2bf(acc[ti][tj][r] + bv);
            }
        }
    }
}

// ---------------------------------------------------------------------------
// Transposed-score flash attention, full seq per block.
// Grid (32 bh, 16 qb); 4 waves x 32 queries. Writes split-bf16 ctx.
// ---------------------------------------------------------------------------
__global__ __launch_bounds__(256, 4) void attn_tscore(
    const short* __restrict__ Q, const short* __restrict__ K,
    const short* __restrict__ Vt,
    short* __restrict__ Ch, short* __restrict__ Cl)
{
    __shared__ __attribute__((aligned(16))) char smem[34816];
    short (*Ks)[72] = (short(*)[72])smem;                 // [32 key][64 d]
    short (*Vs)[40] = (short(*)[40])(smem + 4608);        // [64 d][32 key]

    const int bh = blockIdx.x;                // 0..31
    const int qb = blockIdx.y;                // 0..15
    const int bi = bh >> 4, hi_ = bh & 15;

    const short* Qp  = Q  + bh * SEQ * HD;
    const short* Kp  = K  + bh * SEQ * HD;
    const short* Vtp = Vt + bh * HD * SEQ;

    const int tid  = threadIdx.x;
    const int wave = tid >> 6, lane = tid & 63;
    const int l5 = lane & 31, hf = lane >> 5;
    const int q0w = qb * 128 + wave * 32;

    short8 qf[4];
#pragma unroll
    for (int c = 0; c < 4; ++c)
        qf[c] = *(const short8*)&Qp[(q0w + l5) * HD + c * 16 + hf * 8];

    f32x16 oacc0 = (f32x16)(0.f), oacc1 = (f32x16)(0.f);
    float m = -1.0e30f, l = 0.f;

    const int sKr = tid >> 3, sKc = (tid & 7) * 8;
    const int sVr = tid >> 2, sVc = (tid & 3) * 8;

    for (int kc = 0; kc < 64; ++kc) {
        const int kbase = kc * 32;
        __syncthreads();
        *(short8*)&Ks[sKr][sKc] = *(const short8*)&Kp[(kbase + sKr) * HD + sKc];
        *(short8*)&Vs[sVr][sVc] = *(const short8*)&Vtp[sVr * SEQ + kbase + sVc];
        __syncthreads();

        f32x16 sacc = (f32x16)(0.f);
#pragma unroll
        for (int c = 0; c < 4; ++c) {
            const short8 ka = *(const short8*)&Ks[l5][c * 16 + hf * 8];
            sacc = __builtin_amdgcn_mfma_f32_32x32x16_bf16(ka, qf[c], sacc, 0, 0, 0);
        }

        float a0 = fmaxf(sacc[0], sacc[8]),  a1 = fmaxf(sacc[1], sacc[9]);
        float a2 = fmaxf(sacc[2], sacc[10]), a3 = fmaxf(sacc[3], sacc[11]);
        float a4 = fmaxf(sacc[4], sacc[12]), a5 = fmaxf(sacc[5], sacc[13]);
        float a6 = fmaxf(sacc[6], sacc[14]), a7 = fmaxf(sacc[7], sacc[15]);
        a0 = fmaxf(a0, a4); a1 = fmaxf(a1, a5); a2 = fmaxf(a2, a6); a3 = fmaxf(a3, a7);
        a0 = fmaxf(fmaxf(a0, a1), fmaxf(a2, a3));
        a0 = fmaxf(a0, __shfl_xor(a0, 32, 64));
        const float mnew  = fmaxf(m, a0);
        const float alpha = exp2f(m - mnew);

        float p[16];
#pragma unroll
        for (int i = 0; i < 16; ++i) p[i] = exp2f(sacc[i] - mnew);

        float s0 = p[0]+p[8], s1 = p[1]+p[9], s2 = p[2]+p[10], s3 = p[3]+p[11];
        float s4 = p[4]+p[12], s5 = p[5]+p[13], s6 = p[6]+p[14], s7 = p[7]+p[15];
        s0 += s4; s1 += s5; s2 += s6; s3 += s7;
        float rs = (s0 + s1) + (s2 + s3);
        rs += __shfl_xor(rs, 32, 64);
        l = l * alpha + rs;
        m = mnew;

#pragma unroll
        for (int i = 0; i < 16; ++i) { oacc0[i] *= alpha; oacc1[i] *= alpha; }

        unsigned u0 = pkbf(p[0],  p[1]),  u1 = pkbf(p[2],  p[3]);
        unsigned u2 = pkbf(p[4],  p[5]),  u3 = pkbf(p[6],  p[7]);
        unsigned u4 = pkbf(p[8],  p[9]),  u5 = pkbf(p[10], p[11]);
        unsigned u6 = pkbf(p[12], p[13]), u7 = pkbf(p[14], p[15]);
        const unsigned x0 = __shfl_xor(u0, 32, 64), x1 = __shfl_xor(u1, 32, 64);
        const unsigned x2 = __shfl_xor(u2, 32, 64), x3 = __shfl_xor(u3, 32, 64);
        const unsigned x4 = __shfl_xor(u4, 32, 64), x5 = __shfl_xor(u5, 32, 64);
        const unsigned x6 = __shfl_xor(u6, 32, 64), x7 = __shfl_xor(u7, 32, 64);
        int4v pb0 = (int4v){ (int)(hf ? x2 : u0), (int)(hf ? x3 : u1),
                             (int)(hf ? u2 : x0), (int)(hf ? u3 : x1) };
        int4v pb1 = (int4v){ (int)(hf ? x6 : u4), (int)(hf ? x7 : u5),
                             (int)(hf ? u6 : x4), (int)(hf ? u7 : x5) };
        const short8 pbf0 = __builtin_bit_cast(short8, pb0);
        const short8 pbf1 = __builtin_bit_cast(short8, pb1);

        {
            const short8 va00 = *(const short8*)&Vs[l5][hf * 8];
            const short8 va01 = *(const short8*)&Vs[l5][16 + hf * 8];
            oacc0 = __builtin_amdgcn_mfma_f32_32x32x16_bf16(va00, pbf0, oacc0, 0, 0, 0);
            oacc0 = __builtin_amdgcn_mfma_f32_32x32x16_bf16(va01, pbf1, oacc0, 0, 0, 0);
            const short8 va10 = *(const short8*)&Vs[32 + l5][hf * 8];
            const short8 va11 = *(const short8*)&Vs[32 + l5][16 + hf * 8];
            oacc1 = __builtin_amdgcn_mfma_f32_32x32x16_bf16(va10, pbf0, oacc1, 0, 0, 0);
            oacc1 = __builtin_amdgcn_mfma_f32_32x32x16_bf16(va11, pbf1, oacc1, 0, 0, 0);
        }
    }

    // normalize (lane-scalar) then LDS transpose + split-bf16 ctx write
    const float inv = 1.0f / l;
#pragma unroll
    for (int i = 0; i < 16; ++i) { oacc0[i] *= inv; oacc1[i] *= inv; }

    __syncthreads();
    float (*epi)[68] = (float(*)[68])(smem + wave * 8704);
#pragma unroll
    for (int r = 0; r < 16; ++r) {
        const int d = (r & 3) + 8 * (r >> 2) + 4 * hf;
        epi[l5][d]      = oacc0[r];
        epi[l5][32 + d] = oacc1[r];
    }
    __builtin_amdgcn_s_waitcnt(0);
#pragma unroll
    for (int pass = 0; pass < 8; ++pass) {
        const int row = pass * 4 + (lane >> 4);
        const int col = (lane & 15) * 4;
        const float4 v = *(const float4*)&epi[row][col];
        const float o[4] = {v.x, v.y, v.z, v.w};
        short4v hh, ll;
#pragma unroll
        for (int i = 0; i < 4; ++i) {
            hh[i] = f2bf(o[i]);
            ll[i] = f2bf(o[i] - bf2f(hh[i]));
        }
        const size_t co = ((size_t)(bi * SEQ + q0w + row)) * D_MODEL + hi_ * HD + col;
        *(short4v*)&Ch[co] = hh;
        *(short4v*)&Cl[co] = ll;
    }
}

// ---------------------------------------------------------------------------
// Output GEMM, 128x128 tile, global_load_lds, split-bf16 -> fp32 out.
// ---------------------------------------------------------------------------
__global__ __launch_bounds__(256) void out_gemm128(
    const short* __restrict__ Ah, const short* __restrict__ Al,
    const short* __restrict__ Bh, const short* __restrict__ Bl,
    const float* __restrict__ bias, float* __restrict__ out)
{
    __shared__ short AhS[128*32], AlS[128*32], BhS[128*32], BlS[128*32];

    const int tid  = threadIdx.x;
    const int wave = tid >> 6, lane = tid & 63;
    const int q4 = lane >> 4, l16 = lane & 15;
    const int m0 = blockIdx.y * 128, n0 = blockIdx.x * 128;
    const int rw = (wave & 1) * 64, cw = (wave >> 1) * 64;
    const int trow = tid >> 2;
    const int tcol = (tid & 3) * 8;

    f32x4 acc[4][4];
#pragma unroll
    for (int i = 0; i < 4; ++i)
#pragma unroll
        for (int j = 0; j < 4; ++j) acc[i][j] = (f32x4){0.f, 0.f, 0.f, 0.f};

    for (int kt = 0; kt < D_MODEL; kt += 32) {
        gl16(&Ah[(m0 + trow) * D_MODEL + kt + tcol],      AhS + tid * 8);
        gl16(&Ah[(m0 + 64 + trow) * D_MODEL + kt + tcol], AhS + 2048 + tid * 8);
        gl16(&Al[(m0 + trow) * D_MODEL + kt + tcol],      AlS + tid * 8);
        gl16(&Al[(m0 + 64 + trow) * D_MODEL + kt + tcol], AlS + 2048 + tid * 8);
        gl16(&Bh[(n0 + trow) * D_MODEL + kt + tcol],      BhS + tid * 8);
        gl16(&Bh[(n0 + 64 + trow) * D_MODEL + kt + tcol], BhS + 2048 + tid * 8);
        gl16(&Bl[(n0 + trow) * D_MODEL + kt + tcol],      BlS + tid * 8);
        gl16(&Bl[(n0 + 64 + trow) * D_MODEL + kt + tcol], BlS + 2048 + tid * 8);
        __syncthreads();

        short8 ah[4], al[4], bh[4], bl[4];
#pragma unroll
        for (int t = 0; t < 4; ++t) {
            ah[t] = *(const short8*)&AhS[(rw + t * 16 + l16) * 32 + q4 * 8];
            al[t] = *(const short8*)&AlS[(rw + t * 16 + l16) * 32 + q4 * 8];
            bh[t] = *(const short8*)&BhS[(cw + t * 16 + l16) * 32 + q4 * 8];
            bl[t] = *(const short8*)&BlS[(cw + t * 16 + l16) * 32 + q4 * 8];
        }
#pragma unroll
        for (int ti = 0; ti < 4; ++ti)
#pragma unroll
            for (int tj = 0; tj < 4; ++tj) {
                acc[ti][tj] = __builtin_amdgcn_mfma_f32_16x16x32_bf16(ah[ti], bh[tj], acc[ti][tj], 0, 0, 0);
                acc[ti][tj] = __builtin_amdgcn_mfma_f32_16x16x32_bf16(ah[ti], bl[tj], acc[ti][tj], 0, 0, 0);
                acc[ti][tj] = __builtin_amdgcn_mfma_f32_16x16x32_bf16(al[ti], bh[tj], acc[ti][tj], 0, 0, 0);
            }
        __syncthreads();
    }

#pragma unroll
    for (int tj = 0; tj < 4; ++tj) {
        const int n = n0 + cw + tj * 16 + l16;
        const float bv = bias[n];
#pragma unroll
        for (int ti = 0; ti < 4; ++ti) {
            const int mb = m0 + rw + ti * 16 + q4 * 4;
#pragma unroll
            for (int r = 0; r < 4; ++r)
                out[(mb + r) * D_MODEL + n] = acc[ti][tj][r] + bv;
        }
    }
}

// ---------------------------------------------------------------------------
extern "C" void kernel_launch(void* const* d_in, const int* in_sizes, int n_in,
                              void* d_out, int out_size, void* d_ws, size_t ws_size,
                              hipStream_t stream)
{
    const float* x    = (const float*)d_in[0];
    const float* Wqkv = (const float*)d_in[1];
    const float* bqkv = (const float*)d_in[2];
    const float* Wout = (const float*)d_in[3];
    const float* bout = (const float*)d_in[4];
    float* out = (float*)d_out;

    char* ws = (char*)d_ws;
    short* Qb  = (short*)(ws);                //  8 MB [32][2048][64] (pre-scaled)
    short* Kb  = (short*)(ws +  8*MB);        //  8 MB
    short* Vtb = (short*)(ws + 16*MB);        //  8 MB [32][64][2048]
    short* Woh = (short*)(ws + 24*MB);        //  2 MB Wout^T hi
    short* Wol = (short*)(ws + 26*MB);        //  2 MB Wout^T lo
    short* Ch  = (short*)(ws + 28*MB);        //  8 MB ctx hi
    short* Cl  = (short*)(ws + 36*MB);        //  8 MB ctx lo
    short* Xh  = (short*)(ws + 44*MB);        //  8 MB x hi
    short* Xl  = (short*)(ws + 52*MB);        //  8 MB x lo
    short* Wh  = (short*)(ws + 60*MB);        //  6 MB Wqkv^T hi
    short* Wl  = (short*)(ws + 66*MB);        //  6 MB Wqkv^T lo (end 72 MB)

    prep<<<6144, 256, 0, stream>>>(x, Wqkv, Wout, Xh, Xl, Wh, Wl, Woh, Wol);
    qkv_gemm128<<<dim3(24, 32), 256, 0, stream>>>(Xh, Xl, Wh, Wl, bqkv, Qb, Kb, Vtb);
    attn_tscore<<<dim3(32, 16), 256, 0, stream>>>(Qb, Kb, Vtb, Ch, Cl);
    out_gemm128<<<dim3(8, 32), 256, 0, stream>>>(Ch, Cl, Woh, Wol, bout, out);
}